// Round 1
// 209.589 us; speedup vs baseline: 1.0310x; 1.0310x over previous
//
#include <hip/hip_runtime.h>
#include <cfloat>
#include <cstdint>

// ---------------- problem constants ----------------
#define B_BATCH 32
#define D_DIM   256
#define HW      1024
#define N_POS   32768
#define K_CODES 1024
#define DECAY_F   0.99f
#define ONE_M_DECAY 0.01f
#define EPS_F   1e-5f

// ---------------- output layout (floats) ----------------
#define OUT_Q    0                         // 8388608  quantized_st (B,C,H,W)
#define OUT_LOSS 8388608                   // 1
#define OUT_PERP 8388609                   // 1
#define OUT_CB   8388610                   // 262144   new_codebook
#define OUT_NCS  8650754                   // 1024     new_cluster_size
#define OUT_EDW  8651778                   // 262144   new_ema_dw (dw scratch first)

// OUT_Q region doubles as z bf16 hi/lo scratch (exactly 33,554,432 bytes):
// ztrans writes zhi (16 MB) + zlo (16 MB); argmin_gemm + dw read them;
// fuse overwrites the region with the real output at the end.

// ---------------- workspace layout (bytes) ----------------
#define WS_COUNTS  0          // 1024*4
#define WS_ZNORM   4096       // 4   (sum of ||z||^2, fp32)
#define WS_BSUM    4100       // 4   (sum of best distances)
#define WS_MEMSET  4104       // bytes zeroed at launch
#define WS_CBNORM  4352       // 1024*4
#define WS_OFFS    8448       // 1024*4 (int)
#define WS_CURSOR  12544      // 1024*4 (int)
#define WS_IDX     16640      // 32768*4 (int)
#define WS_SORTED  147712     // 32768*4 (int)
#define WS_CBHI    278784     // 262144*2
#define WS_CBLO    803072     // 262144*2
#define WS_PART    1327360    // 32768*4*8 = 1048576 (u64 partial keys; region is 2MB)
#define WS_SCODE   3424512    // 32768*4 (int, code of each sorted slot)
#define WS_TOTAL   3555584

typedef short s16x8 __attribute__((ext_vector_type(8)));
typedef float f32x4 __attribute__((ext_vector_type(4)));
typedef unsigned long long u64;

__device__ __forceinline__ ushort f2bf_rne(float x) {
    uint u = __float_as_uint(x);
    uint r = (u + 0x7FFF + ((u >> 16) & 1)) >> 16;
    return (ushort)r;
}
__device__ __forceinline__ float bf2f(ushort h) {
    return __uint_as_float(((uint)h) << 16);
}

// async global->LDS, 16 B per lane; LDS dst = wave-uniform base + lane*16
__device__ __forceinline__ void gload16(const void* g, void* l) {
    __builtin_amdgcn_global_load_lds(
        (const __attribute__((address_space(1))) unsigned*)(uintptr_t)g,
        (__attribute__((address_space(3))) unsigned*)(uintptr_t)l, 16, 0, 0);
}

// ============================================================
// prep_ztrans: fused.
//  blocks [0,512):  z (d-major) -> zhi/zlo bf16 (position-major) + sum ||z||^2
//  blocks [512,768): codebook fp32 -> bf16 hi/lo + row norms
__global__ __launch_bounds__(256) void prep_ztrans(const float* __restrict__ z,
                                                   const float* __restrict__ cb,
                                                   ushort* __restrict__ zhi,
                                                   ushort* __restrict__ zlo,
                                                   ushort* __restrict__ cbhi,
                                                   ushort* __restrict__ cblo,
                                                   float* __restrict__ cbnorm,
                                                   float* __restrict__ znorm_acc) {
    __shared__ float Zs[32][65];
    __shared__ float red[256];
    const int tid = threadIdx.x;

    if (blockIdx.x >= 512) {   // ---- prep part ----
        int wave = tid >> 6;
        int lane = tid & 63;
        int k = (blockIdx.x - 512) * 4 + wave;
        float4 v = *(const float4*)&cb[(size_t)k * D_DIM + lane * 4];
        ushort4 h, l;
        h.x = f2bf_rne(v.x); l.x = f2bf_rne(v.x - bf2f(h.x));
        h.y = f2bf_rne(v.y); l.y = f2bf_rne(v.y - bf2f(h.y));
        h.z = f2bf_rne(v.z); l.z = f2bf_rne(v.z - bf2f(h.z));
        h.w = f2bf_rne(v.w); l.w = f2bf_rne(v.w - bf2f(h.w));
        *(ushort4*)&cbhi[(size_t)k * D_DIM + lane * 4] = h;
        *(ushort4*)&cblo[(size_t)k * D_DIM + lane * 4] = l;
        float s = v.x * v.x + v.y * v.y + v.z * v.z + v.w * v.w;
        #pragma unroll
        for (int off = 32; off >= 1; off >>= 1) s += __shfl_xor(s, off);
        if (lane == 0) cbnorm[k] = s;
        return;
    }

    // ---- ztrans part ----
    const int n0  = blockIdx.x * 64;
    const int b   = n0 >> 10;
    const int hw0 = n0 & 1023;
    const float* zb = z + (size_t)b * (D_DIM * HW) + hw0;

    const int zn = tid & 63;
    const int zdb = (tid >> 6) * 8;
    const int n  = tid >> 2;
    const int dq = tid & 3;
    float zsum = 0.f;

    for (int d0 = 0; d0 < D_DIM; d0 += 32) {
        __syncthreads();
        #pragma unroll
        for (int j = 0; j < 8; ++j)
            Zs[zdb + j][zn] = zb[(size_t)(d0 + zdb + j) * HW + zn];
        __syncthreads();
        s16x8 hv, lv;
        #pragma unroll
        for (int j = 0; j < 8; ++j) {
            float f = Zs[dq * 8 + j][n];
            zsum += f * f;
            ushort hb = f2bf_rne(f);
            ushort lb = f2bf_rne(f - bf2f(hb));
            hv[j] = (short)hb;
            lv[j] = (short)lb;
        }
        *(s16x8*)&zhi[(size_t)(n0 + n) * D_DIM + d0 + dq * 8] = hv;
        *(s16x8*)&zlo[(size_t)(n0 + n) * D_DIM + d0 + dq * 8] = lv;
    }
    red[tid] = zsum;
    __syncthreads();
    for (int s2 = 128; s2 >= 1; s2 >>= 1) {
        if (tid < s2) red[tid] += red[tid + s2];
        __syncthreads();
    }
    if (tid == 0) atomicAdd(znorm_acc, red[0]);
}

// ============================================================
// argmin_gemm v2: 256 codes x 128 positions per block, 8 waves, 3-term bf16 MFMA.
// Ring of 3 LDS K-step buffers (48 KB each: Ahi|Alo|Bhi|Blo), prefetch 2 steps
// ahead with counted s_waitcnt vmcnt(6) + raw s_barrier (no vmcnt(0) drain in
// the main loop) + s_setprio around the MFMA cluster.
//
// Race ledger (single barrier / step):
//   stage(t+2) targets buf (t+2)%3 == buf (t-1)%3, whose last reads happened in
//   step t-1; every wave finished step t-1's body before arriving at step t's
//   barrier, and the issue is AFTER that barrier -> write-after-read safe.
//   vmcnt(6): at step-t top each wave has stage(t)'s 6 + stage(t+1)'s 6 loads
//   outstanding; waiting to <=6 retires stage(t) (in-order retirement), and the
//   barrier then publishes it to all waves. Final step uses vmcnt(0).
//
// XCD swizzle: the 4 code-tile blocks of one position-tile share blockIdx&7
// (same XCD under round-robin dispatch) so the z tile stays L2-resident.
__global__ __launch_bounds__(512, 2) void argmin_gemm(const ushort* __restrict__ cbhi,
                                                      const ushort* __restrict__ cblo,
                                                      const ushort* __restrict__ zhi,
                                                      const ushort* __restrict__ zlo,
                                                      const float* __restrict__ cbnorm,
                                                      u64* __restrict__ partial) {
    // 3 * 49152 B ring (kred for the final reduction aliases buffer 0)
    __shared__ __align__(16) ushort lds[73728];

    const int tid  = threadIdx.x;
    const int wave = tid >> 6;
    const int lane = tid & 63;
    const int col  = lane & 15;
    const int lg   = lane >> 4;
    const int wr   = wave >> 1;          // code quarter 0..3 (64 codes)
    const int wc   = wave & 1;           // position half 0..1 (64 positions)
    const int blk  = blockIdx.x;
    const int mt = (blk >> 3) & 3;                       // code tile (256 codes)
    const int pt = (blk & 7) | ((blk >> 5) << 3);        // position tile (128 pos)

    // ---- staging: thread covers slot o_i = i*8192 + tid*16 of the 48KB tile.
    // i=0/1: Ahi rows 0-127 / 128-255; i=2/3: Alo; i=4: Bhi; i=5: Blo.
    // LDS slot (row, G) holds logical group G ^ ((row>>1)&3)  (read uses same XOR).
    const int srow = tid >> 2;                  // 0..127
    const int G    = tid & 3;
    const int sg   = (G ^ ((srow >> 1) & 3)) * 16;   // swizzled source byte group
    const char* pAh = (const char*)cbhi + (size_t)(mt * 256 + srow) * 512 + sg;
    const char* pAl = (const char*)cblo + (size_t)(mt * 256 + srow) * 512 + sg;
    const char* pBh = (const char*)zhi  + (size_t)(pt * 128 + srow) * 512 + sg;
    const char* pBl = (const char*)zlo  + (size_t)(pt * 128 + srow) * 512 + sg;
    char* const ldsw = (char*)lds + wave * 1024;     // wave-uniform dest base

    auto stage = [&](int kt, int bsel) {
        char* d = ldsw + bsel * 49152;
        const int kb = kt * 64;
        gload16(pAh + kb,         d);
        gload16(pAh + kb + 65536, d + 8192);
        gload16(pAl + kb,         d + 16384);
        gload16(pAl + kb + 65536, d + 24576);
        gload16(pBh + kb,         d + 32768);
        gload16(pBl + kb,         d + 40960);
    };

    // ---- fragment read offsets (bytes) within a buffer; swizzle matches stage.
    const char* ldsc = (const char*)lds;
    const int swz  = (lg ^ ((col >> 1) & 3)) * 16;
    const int aoff = (wr * 64 + col) * 64 + swz;     // in Ahi region
    const int boff = (wc * 64 + col) * 64 + swz;     // in Bhi region

    f32x4 acc[4][4];
    #pragma unroll
    for (int mi = 0; mi < 4; ++mi)
        #pragma unroll
        for (int ni = 0; ni < 4; ++ni) acc[mi][ni] = {0.f, 0.f, 0.f, 0.f};

    // prologue: tiles 0,1 in flight
    stage(0, 0);
    stage(1, 1);

    #pragma unroll
    for (int t = 0; t < 8; ++t) {
        const int cur = t % 3;
        if (t < 7) asm volatile("s_waitcnt vmcnt(6)" ::: "memory");
        else       asm volatile("s_waitcnt vmcnt(0)" ::: "memory");
        __builtin_amdgcn_s_barrier();
        __builtin_amdgcn_sched_barrier(0);
        if (t < 6) stage(t + 2, (t + 2) % 3);

        const int base = cur * 49152;
        s16x8 ah[4], al[4], bh[4], bl[4];
        #pragma unroll
        for (int mi = 0; mi < 4; ++mi) {
            ah[mi] = *(const s16x8*)(ldsc + base + aoff + mi * 1024);
            al[mi] = *(const s16x8*)(ldsc + base + 16384 + aoff + mi * 1024);
        }
        #pragma unroll
        for (int ni = 0; ni < 4; ++ni) {
            bh[ni] = *(const s16x8*)(ldsc + base + 32768 + boff + ni * 1024);
            bl[ni] = *(const s16x8*)(ldsc + base + 40960 + boff + ni * 1024);
        }
        __builtin_amdgcn_s_setprio(1);
        #pragma unroll
        for (int mi = 0; mi < 4; ++mi)
            #pragma unroll
            for (int ni = 0; ni < 4; ++ni) {
                acc[mi][ni] = __builtin_amdgcn_mfma_f32_16x16x32_bf16(ah[mi], bh[ni], acc[mi][ni], 0, 0, 0);
                acc[mi][ni] = __builtin_amdgcn_mfma_f32_16x16x32_bf16(ah[mi], bl[ni], acc[mi][ni], 0, 0, 0);
                acc[mi][ni] = __builtin_amdgcn_mfma_f32_16x16x32_bf16(al[mi], bh[ni], acc[mi][ni], 0, 0, 0);
            }
        __builtin_amdgcn_s_setprio(0);
    }

    // ---- argmin epilogue (C layout: code = kbase + mi*16 + lg*4 + r, pos = ni*16 + col)
    const int kbase = mt * 256 + wr * 64;
    u64 best[4] = {~0ull, ~0ull, ~0ull, ~0ull};
    #pragma unroll
    for (int mi = 0; mi < 4; ++mi) {
        float4 cn = *(const float4*)&cbnorm[kbase + mi * 16 + lg * 4];
        const float* cnp = (const float*)&cn;
        #pragma unroll
        for (int ni = 0; ni < 4; ++ni) {
            #pragma unroll
            for (int r = 0; r < 4; ++r) {
                float dist = cnp[r] - 2.f * acc[mi][ni][r];
                uint ub = __float_as_uint(dist);
                ub = ub ^ (uint)(((int)ub >> 31) | 0x80000000);
                u64 key = ((u64)ub << 32) | (uint)(kbase + mi * 16 + lg * 4 + r);
                if (key < best[ni]) best[ni] = key;
            }
        }
    }
    #pragma unroll
    for (int ni = 0; ni < 4; ++ni) {
        u64 o = __shfl_xor(best[ni], 16); if (o < best[ni]) best[ni] = o;
        o = __shfl_xor(best[ni], 32); if (o < best[ni]) best[ni] = o;
    }
    // cross-wave min over the 4 code quarters; kred aliases buffer 0 (free now:
    // buf0's last reads were step 6, all waves passed step 7's barrier since).
    u64* kredp = (u64*)lds;
    if (lane < 16) {
        #pragma unroll
        for (int ni = 0; ni < 4; ++ni)
            kredp[(wc * 64 + ni * 16 + lane) * 4 + wr] = best[ni];
    }
    __syncthreads();
    if (tid < 128) {
        u64 a = kredp[tid * 4 + 0];
        u64 b = kredp[tid * 4 + 1]; if (b < a) a = b;
        b = kredp[tid * 4 + 2]; if (b < a) a = b;
        b = kredp[tid * 4 + 3]; if (b < a) a = b;
        partial[(size_t)(pt * 128 + tid) * 4 + mt] = a;
    }
}

// ============================================================
// combine: min over 4 code-tile partials -> idx; LDS histogram -> counts;
// decode best distance -> block sum -> Sum(bestd) for the loss.
__global__ __launch_bounds__(256) void combine_kernel(const u64* __restrict__ partial,
                                                      int* __restrict__ idx,
                                                      float* __restrict__ counts,
                                                      float* __restrict__ bsum_acc) {
    __shared__ int hist[1024];
    __shared__ float red[256];
    const int tid = threadIdx.x;
    for (int j = tid; j < 1024; j += 256) hist[j] = 0;
    __syncthreads();
    int n = blockIdx.x * 256 + tid;
    const u64* p = partial + (size_t)n * 4;
    u64 m = p[0];
    #pragma unroll
    for (int j = 1; j < 4; ++j) { u64 v = p[j]; if (v < m) m = v; }
    int k = (int)(m & 1023u);
    idx[n] = k;
    atomicAdd(&hist[k], 1);
    // decode monotone u32 -> f32 distance
    uint ub = (uint)(m >> 32);
    uint u = (ub & 0x80000000u) ? (ub ^ 0x80000000u) : ~ub;
    red[tid] = __uint_as_float(u);
    __syncthreads();
    for (int s2 = 128; s2 >= 1; s2 >>= 1) {
        if (tid < s2) red[tid] += red[tid + s2];
        __syncthreads();
    }
    if (tid == 0) atomicAdd(bsum_acc, red[0]);
    for (int j = tid; j < 1024; j += 256) {
        int c = hist[j];
        if (c) atomicAdd(&counts[j], (float)c);
    }
}

// ============================================================
// small: new_cluster_size, perplexity, ntot, loss, prefix-scan offsets/cursor.
__global__ __launch_bounds__(1024) void small_kernel(const float* __restrict__ ema_cs,
                                                     const float* __restrict__ counts,
                                                     const float* __restrict__ znorm,
                                                     const float* __restrict__ bsum,
                                                     float* __restrict__ out_ncs,
                                                     float* __restrict__ out_perp,
                                                     float* __restrict__ out_loss,
                                                     float* __restrict__ ntot_ws,
                                                     int* __restrict__ offsets,
                                                     int* __restrict__ cursor) {
    __shared__ float s1[1024];
    __shared__ float s2[1024];
    __shared__ int   s3[1024];
    int k = threadIdx.x;
    float cnt = counts[k];
    float ncs = ema_cs[k] * DECAY_F + ONE_M_DECAY * cnt;
    out_ncs[k] = ncs;
    float p = cnt / (float)N_POS;
    s1[k] = ncs;
    s2[k] = p * logf(p + 1e-10f);
    int c = (int)cnt;
    s3[k] = c;
    __syncthreads();
    for (int off = 1; off < 1024; off <<= 1) {
        int v = (k >= off) ? s3[k - off] : 0;
        __syncthreads();
        s3[k] += v;
        __syncthreads();
    }
    int excl = s3[k] - c;
    offsets[k] = excl;
    cursor[k] = excl;
    for (int st = 512; st >= 1; st >>= 1) {
        if (k < st) { s1[k] += s1[k + st]; s2[k] += s2[k + st]; }
        __syncthreads();
    }
    if (k == 0) {
        ntot_ws[0] = s1[0];
        out_perp[0] = expf(-s2[0]);
        out_loss[0] = 0.25f * (znorm[0] + bsum[0]) / 8388608.0f;
    }
}

// ============================================================
// scatter: block-aggregated bucket sort; also zeroes the dw scratch region.
__global__ __launch_bounds__(256) void scatter_kernel(const int* __restrict__ idx,
                                                      int* __restrict__ cursor,
                                                      int* __restrict__ sorted,
                                                      int* __restrict__ scode,
                                                      float* __restrict__ dw_zero) {
    __shared__ int hist[1024];
    __shared__ int base_s[1024];
    const int tid = threadIdx.x;
    // zero the dw scratch (262144 floats / 128 blocks = 8 per thread)
    {
        float4 z4 = {0.f, 0.f, 0.f, 0.f};
        size_t e = ((size_t)blockIdx.x * 256 + tid) * 8;
        *(float4*)&dw_zero[e] = z4;
        *(float4*)&dw_zero[e + 4] = z4;
    }
    for (int j = tid; j < 1024; j += 256) hist[j] = 0;
    __syncthreads();
    int n = blockIdx.x * 256 + tid;
    int k = idx[n];
    atomicAdd(&hist[k], 1);
    __syncthreads();
    for (int j = tid; j < 1024; j += 256) {
        int c = hist[j];
        if (c) base_s[j] = atomicAdd(&cursor[j], c);
        hist[j] = 0;
    }
    __syncthreads();
    int rank = atomicAdd(&hist[k], 1);
    int pos = base_s[k] + rank;
    sorted[pos] = n;
    scode[pos] = k;
}

// ============================================================
// dw_chunk: uniform chunks of the SORTED array. Complete segments store
// directly; chunk-spanning runs atomicAdd. dw pre-zeroed by scatter.
#define DW_CHUNK 64
__global__ __launch_bounds__(256) void dw_chunk_kernel(const ushort* __restrict__ zhi,
                                                       const ushort* __restrict__ zlo,
                                                       const int* __restrict__ sorted,
                                                       const int* __restrict__ scode,
                                                       const int* __restrict__ offsets,
                                                       const float* __restrict__ counts,
                                                       float* __restrict__ dw) {
    __shared__ int sid[DW_CHUNK];
    __shared__ int sk[DW_CHUNK];
    const int tid = threadIdx.x;
    const int p0 = blockIdx.x * DW_CHUNK;
    if (tid < DW_CHUNK) {
        sid[tid] = sorted[p0 + tid];
        sk[tid]  = scode[p0 + tid];
    }
    __syncthreads();
    float acc = 0.f;
    int runstart = 0;
    #pragma unroll 4
    for (int i = 0; i < DW_CHUNK; ++i) {
        int id = sid[i];
        float zv = bf2f(zhi[(size_t)id * D_DIM + tid]) + bf2f(zlo[(size_t)id * D_DIM + tid]);
        acc += zv;
        bool end = (i == DW_CHUNK - 1) || (sk[i + 1] != sk[i]);
        if (end) {
            int k = sk[i];
            int off = offsets[k];
            int cnt = (int)counts[k];
            if (p0 + runstart == off && p0 + i == off + cnt - 1)
                dw[(size_t)k * D_DIM + tid] = acc;
            else
                atomicAdd(&dw[(size_t)k * D_DIM + tid], acc);
            acc = 0.f;
            runstart = i + 1;
        }
    }
}

// ============================================================
// fuse_lite: gather codebook rows -> outq in d-major layout. No z read:
// zp + (q - zp) == q to within 1 ulp, far below threshold.
__global__ __launch_bounds__(256) void fuse_lite(const float* __restrict__ cb,
                                                 const int* __restrict__ idx,
                                                 float* __restrict__ outq) {
    __shared__ float Qs[32][65];
    __shared__ int kidx[64];
    const int tid = threadIdx.x;
    const int n0  = blockIdx.x * 64;
    const int b   = n0 >> 10;
    const int hw0 = n0 & 1023;
    float* ob = outq + (size_t)b * (D_DIM * HW) + hw0;

    if (tid < 64) kidx[tid] = idx[n0 + tid];

    for (int d0 = 0; d0 < D_DIM; d0 += 32) {
        __syncthreads();   // protects Qs reuse (and kidx on first iter)
        #pragma unroll
        for (int h = 0; h < 2; ++h) {
            int s  = tid + 256 * h;
            int n  = s >> 3;
            int dq = s & 7;
            int k  = kidx[n];
            float4 q = *(const float4*)&cb[(size_t)k * D_DIM + d0 + dq * 4];
            Qs[dq * 4 + 0][n] = q.x;
            Qs[dq * 4 + 1][n] = q.y;
            Qs[dq * 4 + 2][n] = q.z;
            Qs[dq * 4 + 3][n] = q.w;
        }
        __syncthreads();
        #pragma unroll
        for (int j = 0; j < 8; ++j) {
            int v = tid + 256 * j;
            int d = v >> 6;
            int n = v & 63;
            ob[(size_t)(d0 + d) * HW + n] = Qs[d][n];
        }
    }
}

// ============================================================
// finalize_rows: new_ema_dw (in place) and new_codebook.
__global__ __launch_bounds__(256) void finalize_rows(const float* __restrict__ ema_dw,
                                                     const float* __restrict__ out_ncs,
                                                     const float* __restrict__ ntot_ws,
                                                     float* __restrict__ out_edw,
                                                     float* __restrict__ out_cb) {
    int k = blockIdx.x;
    int d = threadIdx.x;
    float ncs = out_ncs[k];
    float nt = ntot_ws[0];
    float csz = (ncs + EPS_F) / (nt + (float)K_CODES * EPS_F) * nt;
    size_t e = (size_t)k * D_DIM + d;
    float ed = ema_dw[e] * DECAY_F + ONE_M_DECAY * out_edw[e];
    out_edw[e] = ed;
    out_cb[e] = ed / csz;
}

// ============================================================
extern "C" void kernel_launch(void* const* d_in, const int* in_sizes, int n_in,
                              void* d_out, int out_size, void* d_ws, size_t ws_size,
                              hipStream_t stream) {
    const float* z       = (const float*)d_in[0];
    const float* cb      = (const float*)d_in[1];
    const float* ema_cs  = (const float*)d_in[2];
    const float* ema_dw  = (const float*)d_in[3];
    float* out = (float*)d_out;

    char* ws = (char*)d_ws;
    float* ws_counts = (float*)(ws + WS_COUNTS);
    float* ws_znorm  = (float*)(ws + WS_ZNORM);
    float* ws_bsum   = (float*)(ws + WS_BSUM);
    float* ws_cbnorm = (float*)(ws + WS_CBNORM);
    int*   ws_offs   = (int*)(ws + WS_OFFS);
    int*   ws_cursor = (int*)(ws + WS_CURSOR);
    int*   ws_idx    = (int*)(ws + WS_IDX);
    int*   ws_sorted = (int*)(ws + WS_SORTED);
    ushort* ws_cbhi  = (ushort*)(ws + WS_CBHI);
    ushort* ws_cblo  = (ushort*)(ws + WS_CBLO);
    u64*   ws_part   = (u64*)(ws + WS_PART);
    int*   ws_scode  = (int*)(ws + WS_SCODE);

    // zhi/zlo scratch lives in the OUT_Q region (exactly 32 MB)
    ushort* zhi = (ushort*)out;
    ushort* zlo = zhi + 8388608;

    hipMemsetAsync(d_ws, 0, WS_MEMSET, stream);

    prep_ztrans<<<768, 256, 0, stream>>>(z, cb, zhi, zlo, ws_cbhi, ws_cblo,
                                         ws_cbnorm, ws_znorm);
    argmin_gemm<<<1024, 512, 0, stream>>>(ws_cbhi, ws_cblo, zhi, zlo, ws_cbnorm, ws_part);
    combine_kernel<<<N_POS / 256, 256, 0, stream>>>(ws_part, ws_idx, ws_counts, ws_bsum);
    small_kernel<<<1, 1024, 0, stream>>>(ema_cs, ws_counts, ws_znorm, ws_bsum,
                                         out + OUT_NCS, out + OUT_PERP, out + OUT_LOSS,
                                         (float*)(ws + WS_ZNORM) + 1024, ws_offs, ws_cursor);
    scatter_kernel<<<N_POS / 256, 256, 0, stream>>>(ws_idx, ws_cursor, ws_sorted,
                                                    ws_scode, out + OUT_EDW);
    dw_chunk_kernel<<<N_POS / DW_CHUNK, 256, 0, stream>>>(zhi, zlo, ws_sorted, ws_scode,
                                                          ws_offs, ws_counts, out + OUT_EDW);
    fuse_lite<<<N_POS / 64, 256, 0, stream>>>(cb, ws_idx, out + OUT_Q);
    finalize_rows<<<K_CODES, 256, 0, stream>>>(ema_dw, out + OUT_NCS,
                                               (float*)(ws + WS_ZNORM) + 1024,
                                               out + OUT_EDW, out + OUT_CB);
}

// Round 2
// 204.794 us; speedup vs baseline: 1.0551x; 1.0234x over previous
//
#include <hip/hip_runtime.h>
#include <cfloat>
#include <cstdint>

// ---------------- problem constants ----------------
#define B_BATCH 32
#define D_DIM   256
#define HW      1024
#define N_POS   32768
#define K_CODES 1024
#define DECAY_F   0.99f
#define ONE_M_DECAY 0.01f
#define EPS_F   1e-5f

// ---------------- output layout (floats) ----------------
#define OUT_Q    0                         // 8388608  quantized_st (B,C,H,W)
#define OUT_LOSS 8388608                   // 1
#define OUT_PERP 8388609                   // 1
#define OUT_CB   8388610                   // 262144   new_codebook
#define OUT_NCS  8650754                   // 1024     new_cluster_size
#define OUT_EDW  8651778                   // 262144   new_ema_dw (dw scratch first)

// OUT_Q region doubles as z bf16 hi/lo scratch (exactly 33,554,432 bytes):
// ztrans writes zhi (16 MB) + zlo (16 MB); argmin_gemm + dw read them;
// tail_fused overwrites the region with the real output at the end.

// ---------------- workspace layout (bytes) ----------------
#define WS_COUNTS  0          // 1024*4
#define WS_ZNORM   4096       // 4   (sum of ||z||^2, fp32)
#define WS_BSUM    4100       // 4   (sum of best distances)
#define WS_MEMSET  4104       // bytes zeroed at launch
#define WS_CBNORM  4352       // 1024*4
#define WS_OFFS    8448       // 1024*4 (int)
#define WS_CURSOR  12544      // 1024*4 (int)
#define WS_IDX     16640      // 32768*4 (int)
#define WS_SORTED  147712     // 32768*4 (int)
#define WS_CBHI    278784     // 262144*2
#define WS_CBLO    803072     // 262144*2
#define WS_PART    1327360    // 32768*4*8 = 1048576 (u64 partial keys; region is 2MB)
#define WS_SCODE   3424512    // 32768*4 (int, code of each sorted slot)
#define WS_TOTAL   3555584

typedef short s16x8 __attribute__((ext_vector_type(8)));
typedef float f32x4 __attribute__((ext_vector_type(4)));
typedef unsigned long long u64;

__device__ __forceinline__ ushort f2bf_rne(float x) {
    uint u = __float_as_uint(x);
    uint r = (u + 0x7FFF + ((u >> 16) & 1)) >> 16;
    return (ushort)r;
}
__device__ __forceinline__ float bf2f(ushort h) {
    return __uint_as_float(((uint)h) << 16);
}

// async global->LDS, 16 B per lane; LDS dst = wave-uniform base + lane*16
__device__ __forceinline__ void gload16(const void* g, void* l) {
    __builtin_amdgcn_global_load_lds(
        (const __attribute__((address_space(1))) unsigned*)(uintptr_t)g,
        (__attribute__((address_space(3))) unsigned*)(uintptr_t)l, 16, 0, 0);
}

// ============================================================
// prep_ztrans: fused.
//  blocks [0,512):  z (d-major) -> zhi/zlo bf16 (position-major) + sum ||z||^2
//  blocks [512,768): codebook fp32 -> bf16 hi/lo + row norms
__global__ __launch_bounds__(256) void prep_ztrans(const float* __restrict__ z,
                                                   const float* __restrict__ cb,
                                                   ushort* __restrict__ zhi,
                                                   ushort* __restrict__ zlo,
                                                   ushort* __restrict__ cbhi,
                                                   ushort* __restrict__ cblo,
                                                   float* __restrict__ cbnorm,
                                                   float* __restrict__ znorm_acc) {
    __shared__ float Zs[32][65];
    __shared__ float red[256];
    const int tid = threadIdx.x;

    if (blockIdx.x >= 512) {   // ---- prep part ----
        int wave = tid >> 6;
        int lane = tid & 63;
        int k = (blockIdx.x - 512) * 4 + wave;
        float4 v = *(const float4*)&cb[(size_t)k * D_DIM + lane * 4];
        ushort4 h, l;
        h.x = f2bf_rne(v.x); l.x = f2bf_rne(v.x - bf2f(h.x));
        h.y = f2bf_rne(v.y); l.y = f2bf_rne(v.y - bf2f(h.y));
        h.z = f2bf_rne(v.z); l.z = f2bf_rne(v.z - bf2f(h.z));
        h.w = f2bf_rne(v.w); l.w = f2bf_rne(v.w - bf2f(h.w));
        *(ushort4*)&cbhi[(size_t)k * D_DIM + lane * 4] = h;
        *(ushort4*)&cblo[(size_t)k * D_DIM + lane * 4] = l;
        float s = v.x * v.x + v.y * v.y + v.z * v.z + v.w * v.w;
        #pragma unroll
        for (int off = 32; off >= 1; off >>= 1) s += __shfl_xor(s, off);
        if (lane == 0) cbnorm[k] = s;
        return;
    }

    // ---- ztrans part ----
    const int n0  = blockIdx.x * 64;
    const int b   = n0 >> 10;
    const int hw0 = n0 & 1023;
    const float* zb = z + (size_t)b * (D_DIM * HW) + hw0;

    const int zn = tid & 63;
    const int zdb = (tid >> 6) * 8;
    const int n  = tid >> 2;
    const int dq = tid & 3;
    float zsum = 0.f;

    for (int d0 = 0; d0 < D_DIM; d0 += 32) {
        __syncthreads();
        #pragma unroll
        for (int j = 0; j < 8; ++j)
            Zs[zdb + j][zn] = zb[(size_t)(d0 + zdb + j) * HW + zn];
        __syncthreads();
        s16x8 hv, lv;
        #pragma unroll
        for (int j = 0; j < 8; ++j) {
            float f = Zs[dq * 8 + j][n];
            zsum += f * f;
            ushort hb = f2bf_rne(f);
            ushort lb = f2bf_rne(f - bf2f(hb));
            hv[j] = (short)hb;
            lv[j] = (short)lb;
        }
        *(s16x8*)&zhi[(size_t)(n0 + n) * D_DIM + d0 + dq * 8] = hv;
        *(s16x8*)&zlo[(size_t)(n0 + n) * D_DIM + d0 + dq * 8] = lv;
    }
    red[tid] = zsum;
    __syncthreads();
    for (int s2 = 128; s2 >= 1; s2 >>= 1) {
        if (tid < s2) red[tid] += red[tid + s2];
        __syncthreads();
    }
    if (tid == 0) atomicAdd(znorm_acc, red[0]);
}

// ============================================================
// argmin_gemm v3: 256 codes x 128 positions per block, 8 waves, 3-term bf16 MFMA.
// Ring of 3 LDS K-step buffers (48 KB each), counted s_waitcnt vmcnt(6),
// raw s_barrier, and a 4-phase dependency-shaped inner step:
//   P0: 8 ds_reads (ah/al[0,1], bh/bl[0,1]) + half stage -> 12 MFMA (Q00)
//   P1: 4 ds_reads (bh/bl[2,3])             + half stage -> 12 MFMA (Q01)
//   P2: 4 ds_reads (ah/al[2,3])                           -> 12 MFMA (Q11)
//   P3: (operands live)                                   -> 12 MFMA (Q10)
// Each acc[mi][ni] receives the identical MFMA sequence as v2 (numerics-exact);
// only the cross-accumulator cluster order changed, so ds_read latency hides
// under the previous cluster's MFMA drain.
//
// Race ledger (single barrier / step): stage(t+2) targets buf (t-1)%3, last
// read in step t-1; all waves passed step t's barrier after finishing t-1.
// vmcnt(6): retires stage(t) (oldest 6), keeps stage(t+1) in flight.
__global__ __launch_bounds__(512, 2) void argmin_gemm(const ushort* __restrict__ cbhi,
                                                      const ushort* __restrict__ cblo,
                                                      const ushort* __restrict__ zhi,
                                                      const ushort* __restrict__ zlo,
                                                      const float* __restrict__ cbnorm,
                                                      u64* __restrict__ partial) {
    // 3 * 49152 B ring (kred for the final reduction aliases buffer 0)
    __shared__ __align__(16) ushort lds[73728];

    const int tid  = threadIdx.x;
    const int wave = tid >> 6;
    const int lane = tid & 63;
    const int col  = lane & 15;
    const int lg   = lane >> 4;
    const int wr   = wave >> 1;          // code quarter 0..3 (64 codes)
    const int wc   = wave & 1;           // position half 0..1 (64 positions)
    const int blk  = blockIdx.x;
    const int mt = (blk >> 3) & 3;                       // code tile (256 codes)
    const int pt = (blk & 7) | ((blk >> 5) << 3);        // position tile (128 pos)

    // ---- staging: thread covers slot o_i = i*8192 + tid*16 of the 48KB tile.
    // i=0/1: Ahi rows 0-127 / 128-255; i=2/3: Alo; i=4: Bhi; i=5: Blo.
    // LDS slot (row, G) holds logical group G ^ ((row>>1)&3)  (read uses same XOR).
    const int srow = tid >> 2;                  // 0..127
    const int G    = tid & 3;
    const int sg   = (G ^ ((srow >> 1) & 3)) * 16;   // swizzled source byte group
    const char* pAh = (const char*)cbhi + (size_t)(mt * 256 + srow) * 512 + sg;
    const char* pAl = (const char*)cblo + (size_t)(mt * 256 + srow) * 512 + sg;
    const char* pBh = (const char*)zhi  + (size_t)(pt * 128 + srow) * 512 + sg;
    const char* pBl = (const char*)zlo  + (size_t)(pt * 128 + srow) * 512 + sg;
    char* const ldsw = (char*)lds + wave * 1024;     // wave-uniform dest base

    auto stage_a = [&](int kt, int bsel) {           // 3 gloads
        char* d = ldsw + bsel * 49152;
        const int kb = kt * 64;
        gload16(pAh + kb,         d);
        gload16(pAh + kb + 65536, d + 8192);
        gload16(pBh + kb,         d + 32768);
    };
    auto stage_b = [&](int kt, int bsel) {           // 3 gloads
        char* d = ldsw + bsel * 49152;
        const int kb = kt * 64;
        gload16(pAl + kb,         d + 16384);
        gload16(pAl + kb + 65536, d + 24576);
        gload16(pBl + kb,         d + 40960);
    };

    // ---- fragment read offsets (bytes) within a buffer; swizzle matches stage.
    const char* ldsc = (const char*)lds;
    const int swz  = (lg ^ ((col >> 1) & 3)) * 16;
    const int aoff = (wr * 64 + col) * 64 + swz;     // in Ahi region
    const int boff = (wc * 64 + col) * 64 + swz;     // in Bhi region

    f32x4 acc[4][4];
    #pragma unroll
    for (int mi = 0; mi < 4; ++mi)
        #pragma unroll
        for (int ni = 0; ni < 4; ++ni) acc[mi][ni] = {0.f, 0.f, 0.f, 0.f};

    // prologue: tiles 0,1 in flight (6 loads each)
    stage_a(0, 0); stage_b(0, 0);
    stage_a(1, 1); stage_b(1, 1);

#define MM3(mi, ni)                                                                                  \
    acc[mi][ni] = __builtin_amdgcn_mfma_f32_16x16x32_bf16(ah[mi], bh[ni], acc[mi][ni], 0, 0, 0);     \
    acc[mi][ni] = __builtin_amdgcn_mfma_f32_16x16x32_bf16(ah[mi], bl[ni], acc[mi][ni], 0, 0, 0);     \
    acc[mi][ni] = __builtin_amdgcn_mfma_f32_16x16x32_bf16(al[mi], bh[ni], acc[mi][ni], 0, 0, 0);

    #pragma unroll
    for (int t = 0; t < 8; ++t) {
        const int cur = t % 3;
        if (t < 7) asm volatile("s_waitcnt vmcnt(6)" ::: "memory");
        else       asm volatile("s_waitcnt vmcnt(0)" ::: "memory");
        __builtin_amdgcn_s_barrier();
        __builtin_amdgcn_sched_barrier(0);

        const char* bp = ldsc + cur * 49152;
        s16x8 ah[4], al[4], bh[4], bl[4];

        // ---- P0: operands for quadrant (mi 0-1, ni 0-1)
        ah[0] = *(const s16x8*)(bp + aoff);
        al[0] = *(const s16x8*)(bp + 16384 + aoff);
        ah[1] = *(const s16x8*)(bp + aoff + 1024);
        al[1] = *(const s16x8*)(bp + 16384 + aoff + 1024);
        bh[0] = *(const s16x8*)(bp + 32768 + boff);
        bl[0] = *(const s16x8*)(bp + 40960 + boff);
        bh[1] = *(const s16x8*)(bp + 32768 + boff + 1024);
        bl[1] = *(const s16x8*)(bp + 40960 + boff + 1024);
        if (t < 6) stage_a(t + 2, (t + 2) % 3);
        __builtin_amdgcn_s_setprio(1);
        MM3(0, 0) MM3(0, 1) MM3(1, 0) MM3(1, 1)
        __builtin_amdgcn_s_setprio(0);

        // ---- P1: ni 2-3 operands
        bh[2] = *(const s16x8*)(bp + 32768 + boff + 2048);
        bl[2] = *(const s16x8*)(bp + 40960 + boff + 2048);
        bh[3] = *(const s16x8*)(bp + 32768 + boff + 3072);
        bl[3] = *(const s16x8*)(bp + 40960 + boff + 3072);
        if (t < 6) stage_b(t + 2, (t + 2) % 3);
        __builtin_amdgcn_s_setprio(1);
        MM3(0, 2) MM3(0, 3) MM3(1, 2) MM3(1, 3)
        __builtin_amdgcn_s_setprio(0);

        // ---- P2: mi 2-3 operands
        ah[2] = *(const s16x8*)(bp + aoff + 2048);
        al[2] = *(const s16x8*)(bp + 16384 + aoff + 2048);
        ah[3] = *(const s16x8*)(bp + aoff + 3072);
        al[3] = *(const s16x8*)(bp + 16384 + aoff + 3072);
        __builtin_amdgcn_s_setprio(1);
        MM3(2, 2) MM3(2, 3) MM3(3, 2) MM3(3, 3)
        __builtin_amdgcn_s_setprio(0);

        // ---- P3: all operands live
        __builtin_amdgcn_s_setprio(1);
        MM3(2, 0) MM3(2, 1) MM3(3, 0) MM3(3, 1)
        __builtin_amdgcn_s_setprio(0);
    }
#undef MM3

    // ---- argmin epilogue (C layout: code = kbase + mi*16 + lg*4 + r, pos = ni*16 + col)
    const int kbase = mt * 256 + wr * 64;
    u64 best[4] = {~0ull, ~0ull, ~0ull, ~0ull};
    #pragma unroll
    for (int mi = 0; mi < 4; ++mi) {
        float4 cn = *(const float4*)&cbnorm[kbase + mi * 16 + lg * 4];
        const float* cnp = (const float*)&cn;
        #pragma unroll
        for (int ni = 0; ni < 4; ++ni) {
            #pragma unroll
            for (int r = 0; r < 4; ++r) {
                float dist = cnp[r] - 2.f * acc[mi][ni][r];
                uint ub = __float_as_uint(dist);
                ub = ub ^ (uint)(((int)ub >> 31) | 0x80000000);
                u64 key = ((u64)ub << 32) | (uint)(kbase + mi * 16 + lg * 4 + r);
                if (key < best[ni]) best[ni] = key;
            }
        }
    }
    #pragma unroll
    for (int ni = 0; ni < 4; ++ni) {
        u64 o = __shfl_xor(best[ni], 16); if (o < best[ni]) best[ni] = o;
        o = __shfl_xor(best[ni], 32); if (o < best[ni]) best[ni] = o;
    }
    // cross-wave min over the 4 code quarters; kred aliases buffer 0 (free now:
    // buf0's last reads were step 6, all waves passed step 7's barrier since).
    u64* kredp = (u64*)lds;
    if (lane < 16) {
        #pragma unroll
        for (int ni = 0; ni < 4; ++ni)
            kredp[(wc * 64 + ni * 16 + lane) * 4 + wr] = best[ni];
    }
    __syncthreads();
    if (tid < 128) {
        u64 a = kredp[tid * 4 + 0];
        u64 b = kredp[tid * 4 + 1]; if (b < a) a = b;
        b = kredp[tid * 4 + 2]; if (b < a) a = b;
        b = kredp[tid * 4 + 3]; if (b < a) a = b;
        partial[(size_t)(pt * 128 + tid) * 4 + mt] = a;
    }
}

// ============================================================
// combine: min over 4 code-tile partials -> idx; LDS histogram -> counts;
// decode best distance -> block sum -> Sum(bestd) for the loss.
__global__ __launch_bounds__(256) void combine_kernel(const u64* __restrict__ partial,
                                                      int* __restrict__ idx,
                                                      float* __restrict__ counts,
                                                      float* __restrict__ bsum_acc) {
    __shared__ int hist[1024];
    __shared__ float red[256];
    const int tid = threadIdx.x;
    for (int j = tid; j < 1024; j += 256) hist[j] = 0;
    __syncthreads();
    int n = blockIdx.x * 256 + tid;
    const u64* p = partial + (size_t)n * 4;
    u64 m = p[0];
    #pragma unroll
    for (int j = 1; j < 4; ++j) { u64 v = p[j]; if (v < m) m = v; }
    int k = (int)(m & 1023u);
    idx[n] = k;
    atomicAdd(&hist[k], 1);
    // decode monotone u32 -> f32 distance
    uint ub = (uint)(m >> 32);
    uint u = (ub & 0x80000000u) ? (ub ^ 0x80000000u) : ~ub;
    red[tid] = __uint_as_float(u);
    __syncthreads();
    for (int s2 = 128; s2 >= 1; s2 >>= 1) {
        if (tid < s2) red[tid] += red[tid + s2];
        __syncthreads();
    }
    if (tid == 0) atomicAdd(bsum_acc, red[0]);
    for (int j = tid; j < 1024; j += 256) {
        int c = hist[j];
        if (c) atomicAdd(&counts[j], (float)c);
    }
}

// ============================================================
// small: new_cluster_size, perplexity, ntot, loss, prefix-scan offsets/cursor.
__global__ __launch_bounds__(1024) void small_kernel(const float* __restrict__ ema_cs,
                                                     const float* __restrict__ counts,
                                                     const float* __restrict__ znorm,
                                                     const float* __restrict__ bsum,
                                                     float* __restrict__ out_ncs,
                                                     float* __restrict__ out_perp,
                                                     float* __restrict__ out_loss,
                                                     float* __restrict__ ntot_ws,
                                                     int* __restrict__ offsets,
                                                     int* __restrict__ cursor) {
    __shared__ float s1[1024];
    __shared__ float s2[1024];
    __shared__ int   s3[1024];
    int k = threadIdx.x;
    float cnt = counts[k];
    float ncs = ema_cs[k] * DECAY_F + ONE_M_DECAY * cnt;
    out_ncs[k] = ncs;
    float p = cnt / (float)N_POS;
    s1[k] = ncs;
    s2[k] = p * logf(p + 1e-10f);
    int c = (int)cnt;
    s3[k] = c;
    __syncthreads();
    for (int off = 1; off < 1024; off <<= 1) {
        int v = (k >= off) ? s3[k - off] : 0;
        __syncthreads();
        s3[k] += v;
        __syncthreads();
    }
    int excl = s3[k] - c;
    offsets[k] = excl;
    cursor[k] = excl;
    for (int st = 512; st >= 1; st >>= 1) {
        if (k < st) { s1[k] += s1[k + st]; s2[k] += s2[k + st]; }
        __syncthreads();
    }
    if (k == 0) {
        ntot_ws[0] = s1[0];
        out_perp[0] = expf(-s2[0]);
        out_loss[0] = 0.25f * (znorm[0] + bsum[0]) / 8388608.0f;
    }
}

// ============================================================
// scatter: block-aggregated bucket sort; also zeroes the dw scratch region.
__global__ __launch_bounds__(256) void scatter_kernel(const int* __restrict__ idx,
                                                      int* __restrict__ cursor,
                                                      int* __restrict__ sorted,
                                                      int* __restrict__ scode,
                                                      float* __restrict__ dw_zero) {
    __shared__ int hist[1024];
    __shared__ int base_s[1024];
    const int tid = threadIdx.x;
    // zero the dw scratch (262144 floats / 128 blocks = 8 per thread)
    {
        float4 z4 = {0.f, 0.f, 0.f, 0.f};
        size_t e = ((size_t)blockIdx.x * 256 + tid) * 8;
        *(float4*)&dw_zero[e] = z4;
        *(float4*)&dw_zero[e + 4] = z4;
    }
    for (int j = tid; j < 1024; j += 256) hist[j] = 0;
    __syncthreads();
    int n = blockIdx.x * 256 + tid;
    int k = idx[n];
    atomicAdd(&hist[k], 1);
    __syncthreads();
    for (int j = tid; j < 1024; j += 256) {
        int c = hist[j];
        if (c) base_s[j] = atomicAdd(&cursor[j], c);
        hist[j] = 0;
    }
    __syncthreads();
    int rank = atomicAdd(&hist[k], 1);
    int pos = base_s[k] + rank;
    sorted[pos] = n;
    scode[pos] = k;
}

// ============================================================
// dw_chunk: uniform chunks of the SORTED array. Complete segments store
// directly; chunk-spanning runs atomicAdd. dw pre-zeroed by scatter.
#define DW_CHUNK 64
__global__ __launch_bounds__(256) void dw_chunk_kernel(const ushort* __restrict__ zhi,
                                                       const ushort* __restrict__ zlo,
                                                       const int* __restrict__ sorted,
                                                       const int* __restrict__ scode,
                                                       const int* __restrict__ offsets,
                                                       const float* __restrict__ counts,
                                                       float* __restrict__ dw) {
    __shared__ int sid[DW_CHUNK];
    __shared__ int sk[DW_CHUNK];
    const int tid = threadIdx.x;
    const int p0 = blockIdx.x * DW_CHUNK;
    if (tid < DW_CHUNK) {
        sid[tid] = sorted[p0 + tid];
        sk[tid]  = scode[p0 + tid];
    }
    __syncthreads();
    float acc = 0.f;
    int runstart = 0;
    #pragma unroll 4
    for (int i = 0; i < DW_CHUNK; ++i) {
        int id = sid[i];
        float zv = bf2f(zhi[(size_t)id * D_DIM + tid]) + bf2f(zlo[(size_t)id * D_DIM + tid]);
        acc += zv;
        bool end = (i == DW_CHUNK - 1) || (sk[i + 1] != sk[i]);
        if (end) {
            int k = sk[i];
            int off = offsets[k];
            int cnt = (int)counts[k];
            if (p0 + runstart == off && p0 + i == off + cnt - 1)
                dw[(size_t)k * D_DIM + tid] = acc;
            else
                atomicAdd(&dw[(size_t)k * D_DIM + tid], acc);
            acc = 0.f;
            runstart = i + 1;
        }
    }
}

// ============================================================
// tail_fused: blocks [0,512) = fuse_lite (gather codebook rows -> outq,
// d-major; zp + (q - zp) == q to 1 ulp so no z read); blocks [512,1536) =
// finalize_rows (new_ema_dw in place and new_codebook). Both depend only on
// dw_chunk having completed; merged to save one dispatch.
__global__ __launch_bounds__(256) void tail_fused(const float* __restrict__ cb,
                                                  const int* __restrict__ idx,
                                                  float* __restrict__ outq,
                                                  const float* __restrict__ ema_dw,
                                                  const float* __restrict__ out_ncs,
                                                  const float* __restrict__ ntot_ws,
                                                  float* __restrict__ out_edw,
                                                  float* __restrict__ out_cb) {
    const int tid = threadIdx.x;
    if (blockIdx.x >= 512) {      // ---- finalize part ----
        int k = blockIdx.x - 512;
        int d = tid;
        float ncs = out_ncs[k];
        float nt = ntot_ws[0];
        float csz = (ncs + EPS_F) / (nt + (float)K_CODES * EPS_F) * nt;
        size_t e = (size_t)k * D_DIM + d;
        float ed = ema_dw[e] * DECAY_F + ONE_M_DECAY * out_edw[e];
        out_edw[e] = ed;
        out_cb[e] = ed / csz;
        return;
    }

    // ---- fuse part ----
    __shared__ float Qs[32][65];
    __shared__ int kidx[64];
    const int n0  = blockIdx.x * 64;
    const int b   = n0 >> 10;
    const int hw0 = n0 & 1023;
    float* ob = outq + (size_t)b * (D_DIM * HW) + hw0;

    if (tid < 64) kidx[tid] = idx[n0 + tid];

    for (int d0 = 0; d0 < D_DIM; d0 += 32) {
        __syncthreads();   // protects Qs reuse (and kidx on first iter)
        #pragma unroll
        for (int h = 0; h < 2; ++h) {
            int s  = tid + 256 * h;
            int n  = s >> 3;
            int dq = s & 7;
            int k  = kidx[n];
            float4 q = *(const float4*)&cb[(size_t)k * D_DIM + d0 + dq * 4];
            Qs[dq * 4 + 0][n] = q.x;
            Qs[dq * 4 + 1][n] = q.y;
            Qs[dq * 4 + 2][n] = q.z;
            Qs[dq * 4 + 3][n] = q.w;
        }
        __syncthreads();
        #pragma unroll
        for (int j = 0; j < 8; ++j) {
            int v = tid + 256 * j;
            int d = v >> 6;
            int n = v & 63;
            ob[(size_t)(d0 + d) * HW + n] = Qs[d][n];
        }
    }
}

// ============================================================
extern "C" void kernel_launch(void* const* d_in, const int* in_sizes, int n_in,
                              void* d_out, int out_size, void* d_ws, size_t ws_size,
                              hipStream_t stream) {
    const float* z       = (const float*)d_in[0];
    const float* cb      = (const float*)d_in[1];
    const float* ema_cs  = (const float*)d_in[2];
    const float* ema_dw  = (const float*)d_in[3];
    float* out = (float*)d_out;

    char* ws = (char*)d_ws;
    float* ws_counts = (float*)(ws + WS_COUNTS);
    float* ws_znorm  = (float*)(ws + WS_ZNORM);
    float* ws_bsum   = (float*)(ws + WS_BSUM);
    float* ws_cbnorm = (float*)(ws + WS_CBNORM);
    int*   ws_offs   = (int*)(ws + WS_OFFS);
    int*   ws_cursor = (int*)(ws + WS_CURSOR);
    int*   ws_idx    = (int*)(ws + WS_IDX);
    int*   ws_sorted = (int*)(ws + WS_SORTED);
    ushort* ws_cbhi  = (ushort*)(ws + WS_CBHI);
    ushort* ws_cblo  = (ushort*)(ws + WS_CBLO);
    u64*   ws_part   = (u64*)(ws + WS_PART);
    int*   ws_scode  = (int*)(ws + WS_SCODE);

    // zhi/zlo scratch lives in the OUT_Q region (exactly 32 MB)
    ushort* zhi = (ushort*)out;
    ushort* zlo = zhi + 8388608;

    hipMemsetAsync(d_ws, 0, WS_MEMSET, stream);

    prep_ztrans<<<768, 256, 0, stream>>>(z, cb, zhi, zlo, ws_cbhi, ws_cblo,
                                         ws_cbnorm, ws_znorm);
    argmin_gemm<<<1024, 512, 0, stream>>>(ws_cbhi, ws_cblo, zhi, zlo, ws_cbnorm, ws_part);
    combine_kernel<<<N_POS / 256, 256, 0, stream>>>(ws_part, ws_idx, ws_counts, ws_bsum);
    small_kernel<<<1, 1024, 0, stream>>>(ema_cs, ws_counts, ws_znorm, ws_bsum,
                                         out + OUT_NCS, out + OUT_PERP, out + OUT_LOSS,
                                         (float*)(ws + WS_ZNORM) + 1024, ws_offs, ws_cursor);
    scatter_kernel<<<N_POS / 256, 256, 0, stream>>>(ws_idx, ws_cursor, ws_sorted,
                                                    ws_scode, out + OUT_EDW);
    dw_chunk_kernel<<<N_POS / DW_CHUNK, 256, 0, stream>>>(zhi, zlo, ws_sorted, ws_scode,
                                                          ws_offs, ws_counts, out + OUT_EDW);
    tail_fused<<<1536, 256, 0, stream>>>(cb, ws_idx, out + OUT_Q, ema_dw, out + OUT_NCS,
                                         (float*)(ws + WS_ZNORM) + 1024,
                                         out + OUT_EDW, out + OUT_CB);
}

// Round 3
// 203.905 us; speedup vs baseline: 1.0597x; 1.0044x over previous
//
#include <hip/hip_runtime.h>
#include <cfloat>
#include <cstdint>

// ---------------- problem constants ----------------
#define B_BATCH 32
#define D_DIM   256
#define HW      1024
#define N_POS   32768
#define K_CODES 1024
#define DECAY_F   0.99f
#define ONE_M_DECAY 0.01f
#define EPS_F   1e-5f

// ---------------- output layout (floats) ----------------
#define OUT_Q    0                         // 8388608  quantized_st (B,C,H,W)
#define OUT_LOSS 8388608                   // 1
#define OUT_PERP 8388609                   // 1
#define OUT_CB   8388610                   // 262144   new_codebook
#define OUT_NCS  8650754                   // 1024     new_cluster_size
#define OUT_EDW  8651778                   // 262144   new_ema_dw (dw scratch first)

// OUT_Q region doubles as z bf16 hi/lo scratch (exactly 33,554,432 bytes):
// ztrans writes zhi (16 MB) + zlo (16 MB); argmin_gemm + dw read them;
// tail_fused overwrites the region with the real output at the end.

// ---------------- workspace layout (bytes) ----------------
#define WS_COUNTS  0          // 1024*4
#define WS_ZNORM   4096       // 4   (sum of ||z||^2, fp32)
#define WS_BSUM    4100       // 4   (sum of best distances)
#define WS_MEMSET  4104       // bytes zeroed at launch
#define WS_CBNORM  4352       // 1024*4
#define WS_OFFS    8448       // 1024*4 (int)
#define WS_CURSOR  12544      // 1024*4 (int)
#define WS_IDX     16640      // 32768*4 (int)
#define WS_SORTED  147712     // 32768*4 (int)
#define WS_CBHI    278784     // 262144*2
#define WS_CBLO    803072     // 262144*2
#define WS_PART    1327360    // 32768*8*8 = 2097152 (u64 partial keys)
#define WS_SCODE   3424512    // 32768*4 (int, code of each sorted slot)
#define WS_TOTAL   3555584

typedef short s16x8 __attribute__((ext_vector_type(8)));
typedef float f32x4 __attribute__((ext_vector_type(4)));
typedef unsigned long long u64;

__device__ __forceinline__ ushort f2bf_rne(float x) {
    uint u = __float_as_uint(x);
    uint r = (u + 0x7FFF + ((u >> 16) & 1)) >> 16;
    return (ushort)r;
}
__device__ __forceinline__ float bf2f(ushort h) {
    return __uint_as_float(((uint)h) << 16);
}

// async global->LDS, 16 B per lane; LDS dst = wave-uniform base + lane*16
__device__ __forceinline__ void gload16(const void* g, void* l) {
    __builtin_amdgcn_global_load_lds(
        (const __attribute__((address_space(1))) unsigned*)(uintptr_t)g,
        (__attribute__((address_space(3))) unsigned*)(uintptr_t)l, 16, 0, 0);
}

// ============================================================
// prep_ztrans: fused.
//  blocks [0,512):  z (d-major) -> zhi/zlo bf16 (position-major) + sum ||z||^2
//  blocks [512,768): codebook fp32 -> bf16 hi/lo + row norms
__global__ __launch_bounds__(256) void prep_ztrans(const float* __restrict__ z,
                                                   const float* __restrict__ cb,
                                                   ushort* __restrict__ zhi,
                                                   ushort* __restrict__ zlo,
                                                   ushort* __restrict__ cbhi,
                                                   ushort* __restrict__ cblo,
                                                   float* __restrict__ cbnorm,
                                                   float* __restrict__ znorm_acc) {
    __shared__ float Zs[32][65];
    __shared__ float red[256];
    const int tid = threadIdx.x;

    if (blockIdx.x >= 512) {   // ---- prep part ----
        int wave = tid >> 6;
        int lane = tid & 63;
        int k = (blockIdx.x - 512) * 4 + wave;
        float4 v = *(const float4*)&cb[(size_t)k * D_DIM + lane * 4];
        ushort4 h, l;
        h.x = f2bf_rne(v.x); l.x = f2bf_rne(v.x - bf2f(h.x));
        h.y = f2bf_rne(v.y); l.y = f2bf_rne(v.y - bf2f(h.y));
        h.z = f2bf_rne(v.z); l.z = f2bf_rne(v.z - bf2f(h.z));
        h.w = f2bf_rne(v.w); l.w = f2bf_rne(v.w - bf2f(h.w));
        *(ushort4*)&cbhi[(size_t)k * D_DIM + lane * 4] = h;
        *(ushort4*)&cblo[(size_t)k * D_DIM + lane * 4] = l;
        float s = v.x * v.x + v.y * v.y + v.z * v.z + v.w * v.w;
        #pragma unroll
        for (int off = 32; off >= 1; off >>= 1) s += __shfl_xor(s, off);
        if (lane == 0) cbnorm[k] = s;
        return;
    }

    // ---- ztrans part ----
    const int n0  = blockIdx.x * 64;
    const int b   = n0 >> 10;
    const int hw0 = n0 & 1023;
    const float* zb = z + (size_t)b * (D_DIM * HW) + hw0;

    const int zn = tid & 63;
    const int zdb = (tid >> 6) * 8;
    const int n  = tid >> 2;
    const int dq = tid & 3;
    float zsum = 0.f;

    for (int d0 = 0; d0 < D_DIM; d0 += 32) {
        __syncthreads();
        #pragma unroll
        for (int j = 0; j < 8; ++j)
            Zs[zdb + j][zn] = zb[(size_t)(d0 + zdb + j) * HW + zn];
        __syncthreads();
        s16x8 hv, lv;
        #pragma unroll
        for (int j = 0; j < 8; ++j) {
            float f = Zs[dq * 8 + j][n];
            zsum += f * f;
            ushort hb = f2bf_rne(f);
            ushort lb = f2bf_rne(f - bf2f(hb));
            hv[j] = (short)hb;
            lv[j] = (short)lb;
        }
        *(s16x8*)&zhi[(size_t)(n0 + n) * D_DIM + d0 + dq * 8] = hv;
        *(s16x8*)&zlo[(size_t)(n0 + n) * D_DIM + d0 + dq * 8] = lv;
    }
    red[tid] = zsum;
    __syncthreads();
    for (int s2 = 128; s2 >= 1; s2 >>= 1) {
        if (tid < s2) red[tid] += red[tid + s2];
        __syncthreads();
    }
    if (tid == 0) atomicAdd(znorm_acc, red[0]);
}

// ============================================================
// argmin_gemm v4: 128 codes x 128 positions per block, 4 waves (2x2 grid,
// each wave 64x64 = M4N4, 48 MFMA/step), 3-term bf16 MFMA, K-step 32.
// Ring-2 of 32 KB buffers = 64 KB LDS -> TWO blocks per CU. The two resident
// blocks run independent barrier schedules, so one block's ds_read burst
// overlaps the other's MFMA burst (the per-CU LDS pipe stays fed).
//
// Per-step ledger (single barrier):
//   vmcnt(0)   : own stage(t) writes landed (stage(t+1) not yet issued)
//   s_barrier  : publishes stage(t) to all waves; also proves every wave
//                finished its step t-1 reads of buf[1-B] (reads complete via
//                lgkmcnt before the t-1 MFMAs, which precede this barrier)
//   stage(t+1) -> buf[1-B]  : write-after-read safe by the above
//   phased reads of buf[B] + MFMA quadrants (dep-shaped, setprio-wrapped)
//
// XCD swizzle: pt low bits = blockIdx&7 = XCD under round-robin dispatch, so
// each XCD's z working set is ~32 pos-tiles (L2-resident); cb (1 MB) resident
// on every XCD.
__global__ __launch_bounds__(256, 2) void argmin_gemm(const ushort* __restrict__ cbhi,
                                                      const ushort* __restrict__ cblo,
                                                      const ushort* __restrict__ zhi,
                                                      const ushort* __restrict__ zlo,
                                                      const float* __restrict__ cbnorm,
                                                      u64* __restrict__ partial) {
    // 2 x 32768 B ring (kred for the final reduction aliases buffer 0)
    __shared__ __align__(16) ushort lds[32768];   // 65536 bytes

    const int tid  = threadIdx.x;
    const int wave = tid >> 6;
    const int lane = tid & 63;
    const int col  = lane & 15;
    const int lg   = lane >> 4;
    const int wr   = wave >> 1;          // code half 0..1 (64 codes)
    const int wc   = wave & 1;           // position half 0..1 (64 positions)
    const int blk  = blockIdx.x;
    const int mt = (blk >> 3) & 7;                       // code tile (128 codes)
    const int pt = (blk & 7) | ((blk >> 6) << 3);        // position tile (128 pos)

    // ---- staging addressing: per step each thread issues 8 gload16s.
    // Buffer layout (32 KB): Ahi[0,8K) Alo[8K,16K) Bhi[16K,24K) Blo[24K,32K).
    // Each region = 128 rows x 64 B; call c in {0,1} covers rows [c*64,c*64+64).
    // Thread: row-in-call = tid>>2, slot G = tid&3; LDS slot (row,G) holds
    // logical 16B-group G ^ ((row>>1)&3)  (read side uses the same XOR).
    const int srow = tid >> 2;                   // 0..63
    const int G    = tid & 3;
    const int sg   = (G ^ ((tid >> 3) & 3)) * 16;    // swizzled source byte group
    const char* pAh = (const char*)cbhi + (size_t)(mt * 128 + srow) * 512 + sg;
    const char* pAl = (const char*)cblo + (size_t)(mt * 128 + srow) * 512 + sg;
    const char* pBh = (const char*)zhi  + (size_t)(pt * 128 + srow) * 512 + sg;
    const char* pBl = (const char*)zlo  + (size_t)(pt * 128 + srow) * 512 + sg;
    char* const ldsw = (char*)lds + wave * 1024;      // wave-uniform dest base

    auto stage_a = [&](int kt, int bsel) {            // Ahi + Alo, 4 gloads
        char* d = ldsw + bsel * 32768;
        const int kb = kt * 64;
        gload16(pAh + kb,         d);                 // rows 0-63
        gload16(pAh + kb + 32768, d + 4096);          // rows 64-127 (+64*512B)
        gload16(pAl + kb,         d + 8192);
        gload16(pAl + kb + 32768, d + 12288);
    };
    auto stage_b = [&](int kt, int bsel) {            // Bhi + Blo, 4 gloads
        char* d = ldsw + bsel * 32768;
        const int kb = kt * 64;
        gload16(pBh + kb,         d + 16384);
        gload16(pBh + kb + 32768, d + 20480);
        gload16(pBl + kb,         d + 24576);
        gload16(pBl + kb + 32768, d + 28672);
    };

    // ---- fragment read offsets (bytes) within a buffer; swizzle matches stage.
    const char* ldsc = (const char*)lds;
    const int swz  = (lg ^ ((col >> 1) & 3)) * 16;
    const int aoff = (wr * 64 + col) * 64 + swz;     // in Ahi region
    const int boff = (wc * 64 + col) * 64 + swz;     // in Bhi region

    f32x4 acc[4][4];
    #pragma unroll
    for (int mi = 0; mi < 4; ++mi)
        #pragma unroll
        for (int ni = 0; ni < 4; ++ni) acc[mi][ni] = {0.f, 0.f, 0.f, 0.f};

    // prologue: tile 0 in flight
    stage_a(0, 0); stage_b(0, 0);

#define MM3(mi, ni)                                                                                  \
    acc[mi][ni] = __builtin_amdgcn_mfma_f32_16x16x32_bf16(ah[mi], bh[ni], acc[mi][ni], 0, 0, 0);     \
    acc[mi][ni] = __builtin_amdgcn_mfma_f32_16x16x32_bf16(ah[mi], bl[ni], acc[mi][ni], 0, 0, 0);     \
    acc[mi][ni] = __builtin_amdgcn_mfma_f32_16x16x32_bf16(al[mi], bh[ni], acc[mi][ni], 0, 0, 0);

    #pragma unroll
    for (int t = 0; t < 8; ++t) {
        asm volatile("s_waitcnt vmcnt(0)" ::: "memory");
        __builtin_amdgcn_s_barrier();
        __builtin_amdgcn_sched_barrier(0);

        const char* bp = ldsc + (t & 1) * 32768;
        s16x8 ah[4], al[4], bh[4], bl[4];

        // ---- P0: operands for quadrant (mi 0-1, ni 0-1) + A-prefetch
        ah[0] = *(const s16x8*)(bp + aoff);
        al[0] = *(const s16x8*)(bp + 8192 + aoff);
        ah[1] = *(const s16x8*)(bp + aoff + 1024);
        al[1] = *(const s16x8*)(bp + 8192 + aoff + 1024);
        bh[0] = *(const s16x8*)(bp + 16384 + boff);
        bl[0] = *(const s16x8*)(bp + 24576 + boff);
        bh[1] = *(const s16x8*)(bp + 16384 + boff + 1024);
        bl[1] = *(const s16x8*)(bp + 24576 + boff + 1024);
        if (t < 7) stage_a(t + 1, (t + 1) & 1);
        __builtin_amdgcn_s_setprio(1);
        MM3(0, 0) MM3(0, 1) MM3(1, 0) MM3(1, 1)
        __builtin_amdgcn_s_setprio(0);

        // ---- P1: ni 2-3 operands + B-prefetch
        bh[2] = *(const s16x8*)(bp + 16384 + boff + 2048);
        bl[2] = *(const s16x8*)(bp + 24576 + boff + 2048);
        bh[3] = *(const s16x8*)(bp + 16384 + boff + 3072);
        bl[3] = *(const s16x8*)(bp + 24576 + boff + 3072);
        if (t < 7) stage_b(t + 1, (t + 1) & 1);
        __builtin_amdgcn_s_setprio(1);
        MM3(0, 2) MM3(0, 3) MM3(1, 2) MM3(1, 3)
        __builtin_amdgcn_s_setprio(0);

        // ---- P2: mi 2-3 operands
        ah[2] = *(const s16x8*)(bp + aoff + 2048);
        al[2] = *(const s16x8*)(bp + 8192 + aoff + 2048);
        ah[3] = *(const s16x8*)(bp + aoff + 3072);
        al[3] = *(const s16x8*)(bp + 8192 + aoff + 3072);
        __builtin_amdgcn_s_setprio(1);
        MM3(2, 2) MM3(2, 3) MM3(3, 2) MM3(3, 3)
        __builtin_amdgcn_s_setprio(0);

        // ---- P3: all operands live
        __builtin_amdgcn_s_setprio(1);
        MM3(2, 0) MM3(2, 1) MM3(3, 0) MM3(3, 1)
        __builtin_amdgcn_s_setprio(0);
    }
#undef MM3

    // ---- argmin epilogue (C layout: code = kbase + mi*16 + lg*4 + r, pos = ni*16 + col)
    const int kbase = mt * 128 + wr * 64;
    u64 best[4] = {~0ull, ~0ull, ~0ull, ~0ull};
    #pragma unroll
    for (int mi = 0; mi < 4; ++mi) {
        float4 cn = *(const float4*)&cbnorm[kbase + mi * 16 + lg * 4];
        const float* cnp = (const float*)&cn;
        #pragma unroll
        for (int ni = 0; ni < 4; ++ni) {
            #pragma unroll
            for (int r = 0; r < 4; ++r) {
                float dist = cnp[r] - 2.f * acc[mi][ni][r];
                uint ub = __float_as_uint(dist);
                ub = ub ^ (uint)(((int)ub >> 31) | 0x80000000);
                u64 key = ((u64)ub << 32) | (uint)(kbase + mi * 16 + lg * 4 + r);
                if (key < best[ni]) best[ni] = key;
            }
        }
    }
    #pragma unroll
    for (int ni = 0; ni < 4; ++ni) {
        u64 o = __shfl_xor(best[ni], 16); if (o < best[ni]) best[ni] = o;
        o = __shfl_xor(best[ni], 32); if (o < best[ni]) best[ni] = o;
    }
    // cross-wave min over the 2 code halves; kred aliases buffer 0 (bytes
    // 0..2047; final step read buffer 1, and every wave passed step 7's
    // barrier before any wave reaches this point).
    u64* kredp = (u64*)lds;
    if (lane < 16) {
        #pragma unroll
        for (int ni = 0; ni < 4; ++ni)
            kredp[(wc * 64 + ni * 16 + lane) * 2 + wr] = best[ni];
    }
    __syncthreads();
    if (tid < 128) {
        u64 a = kredp[tid * 2 + 0];
        u64 b = kredp[tid * 2 + 1]; if (b < a) a = b;
        partial[(size_t)(pt * 128 + tid) * 8 + mt] = a;
    }
}

// ============================================================
// combine: min over 8 code-tile partials -> idx; LDS histogram -> counts;
// decode best distance -> block sum -> Sum(bestd) for the loss.
__global__ __launch_bounds__(256) void combine_kernel(const u64* __restrict__ partial,
                                                      int* __restrict__ idx,
                                                      float* __restrict__ counts,
                                                      float* __restrict__ bsum_acc) {
    __shared__ int hist[1024];
    __shared__ float red[256];
    const int tid = threadIdx.x;
    for (int j = tid; j < 1024; j += 256) hist[j] = 0;
    __syncthreads();
    int n = blockIdx.x * 256 + tid;
    const u64* p = partial + (size_t)n * 8;
    u64 m = p[0];
    #pragma unroll
    for (int j = 1; j < 8; ++j) { u64 v = p[j]; if (v < m) m = v; }
    int k = (int)(m & 1023u);
    idx[n] = k;
    atomicAdd(&hist[k], 1);
    // decode monotone u32 -> f32 distance
    uint ub = (uint)(m >> 32);
    uint u = (ub & 0x80000000u) ? (ub ^ 0x80000000u) : ~ub;
    red[tid] = __uint_as_float(u);
    __syncthreads();
    for (int s2 = 128; s2 >= 1; s2 >>= 1) {
        if (tid < s2) red[tid] += red[tid + s2];
        __syncthreads();
    }
    if (tid == 0) atomicAdd(bsum_acc, red[0]);
    for (int j = tid; j < 1024; j += 256) {
        int c = hist[j];
        if (c) atomicAdd(&counts[j], (float)c);
    }
}

// ============================================================
// small: new_cluster_size, perplexity, ntot, loss, prefix-scan offsets/cursor.
__global__ __launch_bounds__(1024) void small_kernel(const float* __restrict__ ema_cs,
                                                     const float* __restrict__ counts,
                                                     const float* __restrict__ znorm,
                                                     const float* __restrict__ bsum,
                                                     float* __restrict__ out_ncs,
                                                     float* __restrict__ out_perp,
                                                     float* __restrict__ out_loss,
                                                     float* __restrict__ ntot_ws,
                                                     int* __restrict__ offsets,
                                                     int* __restrict__ cursor) {
    __shared__ float s1[1024];
    __shared__ float s2[1024];
    __shared__ int   s3[1024];
    int k = threadIdx.x;
    float cnt = counts[k];
    float ncs = ema_cs[k] * DECAY_F + ONE_M_DECAY * cnt;
    out_ncs[k] = ncs;
    float p = cnt / (float)N_POS;
    s1[k] = ncs;
    s2[k] = p * logf(p + 1e-10f);
    int c = (int)cnt;
    s3[k] = c;
    __syncthreads();
    for (int off = 1; off < 1024; off <<= 1) {
        int v = (k >= off) ? s3[k - off] : 0;
        __syncthreads();
        s3[k] += v;
        __syncthreads();
    }
    int excl = s3[k] - c;
    offsets[k] = excl;
    cursor[k] = excl;
    for (int st = 512; st >= 1; st >>= 1) {
        if (k < st) { s1[k] += s1[k + st]; s2[k] += s2[k + st]; }
        __syncthreads();
    }
    if (k == 0) {
        ntot_ws[0] = s1[0];
        out_perp[0] = expf(-s2[0]);
        out_loss[0] = 0.25f * (znorm[0] + bsum[0]) / 8388608.0f;
    }
}

// ============================================================
// scatter: block-aggregated bucket sort; also zeroes the dw scratch region.
__global__ __launch_bounds__(256) void scatter_kernel(const int* __restrict__ idx,
                                                      int* __restrict__ cursor,
                                                      int* __restrict__ sorted,
                                                      int* __restrict__ scode,
                                                      float* __restrict__ dw_zero) {
    __shared__ int hist[1024];
    __shared__ int base_s[1024];
    const int tid = threadIdx.x;
    // zero the dw scratch (262144 floats / 128 blocks = 8 per thread)
    {
        float4 z4 = {0.f, 0.f, 0.f, 0.f};
        size_t e = ((size_t)blockIdx.x * 256 + tid) * 8;
        *(float4*)&dw_zero[e] = z4;
        *(float4*)&dw_zero[e + 4] = z4;
    }
    for (int j = tid; j < 1024; j += 256) hist[j] = 0;
    __syncthreads();
    int n = blockIdx.x * 256 + tid;
    int k = idx[n];
    atomicAdd(&hist[k], 1);
    __syncthreads();
    for (int j = tid; j < 1024; j += 256) {
        int c = hist[j];
        if (c) base_s[j] = atomicAdd(&cursor[j], c);
        hist[j] = 0;
    }
    __syncthreads();
    int rank = atomicAdd(&hist[k], 1);
    int pos = base_s[k] + rank;
    sorted[pos] = n;
    scode[pos] = k;
}

// ============================================================
// dw_chunk: uniform chunks of the SORTED array. Complete segments store
// directly; chunk-spanning runs atomicAdd. dw pre-zeroed by scatter.
#define DW_CHUNK 64
__global__ __launch_bounds__(256) void dw_chunk_kernel(const ushort* __restrict__ zhi,
                                                       const ushort* __restrict__ zlo,
                                                       const int* __restrict__ sorted,
                                                       const int* __restrict__ scode,
                                                       const int* __restrict__ offsets,
                                                       const float* __restrict__ counts,
                                                       float* __restrict__ dw) {
    __shared__ int sid[DW_CHUNK];
    __shared__ int sk[DW_CHUNK];
    const int tid = threadIdx.x;
    const int p0 = blockIdx.x * DW_CHUNK;
    if (tid < DW_CHUNK) {
        sid[tid] = sorted[p0 + tid];
        sk[tid]  = scode[p0 + tid];
    }
    __syncthreads();
    float acc = 0.f;
    int runstart = 0;
    #pragma unroll 4
    for (int i = 0; i < DW_CHUNK; ++i) {
        int id = sid[i];
        float zv = bf2f(zhi[(size_t)id * D_DIM + tid]) + bf2f(zlo[(size_t)id * D_DIM + tid]);
        acc += zv;
        bool end = (i == DW_CHUNK - 1) || (sk[i + 1] != sk[i]);
        if (end) {
            int k = sk[i];
            int off = offsets[k];
            int cnt = (int)counts[k];
            if (p0 + runstart == off && p0 + i == off + cnt - 1)
                dw[(size_t)k * D_DIM + tid] = acc;
            else
                atomicAdd(&dw[(size_t)k * D_DIM + tid], acc);
            acc = 0.f;
            runstart = i + 1;
        }
    }
}

// ============================================================
// tail_fused: blocks [0,512) = fuse_lite (gather codebook rows -> outq,
// d-major; zp + (q - zp) == q to 1 ulp so no z read); blocks [512,1536) =
// finalize_rows (new_ema_dw in place and new_codebook). Both depend only on
// dw_chunk having completed; merged to save one dispatch.
__global__ __launch_bounds__(256) void tail_fused(const float* __restrict__ cb,
                                                  const int* __restrict__ idx,
                                                  float* __restrict__ outq,
                                                  const float* __restrict__ ema_dw,
                                                  const float* __restrict__ out_ncs,
                                                  const float* __restrict__ ntot_ws,
                                                  float* __restrict__ out_edw,
                                                  float* __restrict__ out_cb) {
    const int tid = threadIdx.x;
    if (blockIdx.x >= 512) {      // ---- finalize part ----
        int k = blockIdx.x - 512;
        int d = tid;
        float ncs = out_ncs[k];
        float nt = ntot_ws[0];
        float csz = (ncs + EPS_F) / (nt + (float)K_CODES * EPS_F) * nt;
        size_t e = (size_t)k * D_DIM + d;
        float ed = ema_dw[e] * DECAY_F + ONE_M_DECAY * out_edw[e];
        out_edw[e] = ed;
        out_cb[e] = ed / csz;
        return;
    }

    // ---- fuse part ----
    __shared__ float Qs[32][65];
    __shared__ int kidx[64];
    const int n0  = blockIdx.x * 64;
    const int b   = n0 >> 10;
    const int hw0 = n0 & 1023;
    float* ob = outq + (size_t)b * (D_DIM * HW) + hw0;

    if (tid < 64) kidx[tid] = idx[n0 + tid];

    for (int d0 = 0; d0 < D_DIM; d0 += 32) {
        __syncthreads();   // protects Qs reuse (and kidx on first iter)
        #pragma unroll
        for (int h = 0; h < 2; ++h) {
            int s  = tid + 256 * h;
            int n  = s >> 3;
            int dq = s & 7;
            int k  = kidx[n];
            float4 q = *(const float4*)&cb[(size_t)k * D_DIM + d0 + dq * 4];
            Qs[dq * 4 + 0][n] = q.x;
            Qs[dq * 4 + 1][n] = q.y;
            Qs[dq * 4 + 2][n] = q.z;
            Qs[dq * 4 + 3][n] = q.w;
        }
        __syncthreads();
        #pragma unroll
        for (int j = 0; j < 8; ++j) {
            int v = tid + 256 * j;
            int d = v >> 6;
            int n = v & 63;
            ob[(size_t)(d0 + d) * HW + n] = Qs[d][n];
        }
    }
}

// ============================================================
extern "C" void kernel_launch(void* const* d_in, const int* in_sizes, int n_in,
                              void* d_out, int out_size, void* d_ws, size_t ws_size,
                              hipStream_t stream) {
    const float* z       = (const float*)d_in[0];
    const float* cb      = (const float*)d_in[1];
    const float* ema_cs  = (const float*)d_in[2];
    const float* ema_dw  = (const float*)d_in[3];
    float* out = (float*)d_out;

    char* ws = (char*)d_ws;
    float* ws_counts = (float*)(ws + WS_COUNTS);
    float* ws_znorm  = (float*)(ws + WS_ZNORM);
    float* ws_bsum   = (float*)(ws + WS_BSUM);
    float* ws_cbnorm = (float*)(ws + WS_CBNORM);
    int*   ws_offs   = (int*)(ws + WS_OFFS);
    int*   ws_cursor = (int*)(ws + WS_CURSOR);
    int*   ws_idx    = (int*)(ws + WS_IDX);
    int*   ws_sorted = (int*)(ws + WS_SORTED);
    ushort* ws_cbhi  = (ushort*)(ws + WS_CBHI);
    ushort* ws_cblo  = (ushort*)(ws + WS_CBLO);
    u64*   ws_part   = (u64*)(ws + WS_PART);
    int*   ws_scode  = (int*)(ws + WS_SCODE);

    // zhi/zlo scratch lives in the OUT_Q region (exactly 32 MB)
    ushort* zhi = (ushort*)out;
    ushort* zlo = zhi + 8388608;

    hipMemsetAsync(d_ws, 0, WS_MEMSET, stream);

    prep_ztrans<<<768, 256, 0, stream>>>(z, cb, zhi, zlo, ws_cbhi, ws_cblo,
                                         ws_cbnorm, ws_znorm);
    argmin_gemm<<<2048, 256, 0, stream>>>(ws_cbhi, ws_cblo, zhi, zlo, ws_cbnorm, ws_part);
    combine_kernel<<<N_POS / 256, 256, 0, stream>>>(ws_part, ws_idx, ws_counts, ws_bsum);
    small_kernel<<<1, 1024, 0, stream>>>(ema_cs, ws_counts, ws_znorm, ws_bsum,
                                         out + OUT_NCS, out + OUT_PERP, out + OUT_LOSS,
                                         (float*)(ws + WS_ZNORM) + 1024, ws_offs, ws_cursor);
    scatter_kernel<<<N_POS / 256, 256, 0, stream>>>(ws_idx, ws_cursor, ws_sorted,
                                                    ws_scode, out + OUT_EDW);
    dw_chunk_kernel<<<N_POS / DW_CHUNK, 256, 0, stream>>>(zhi, zlo, ws_sorted, ws_scode,
                                                          ws_offs, ws_counts, out + OUT_EDW);
    tail_fused<<<1536, 256, 0, stream>>>(cb, ws_idx, out + OUT_Q, ema_dw, out + OUT_NCS,
                                         (float*)(ws + WS_ZNORM) + 1024,
                                         out + OUT_EDW, out + OUT_CB);
}

// Round 4
// 196.733 us; speedup vs baseline: 1.0983x; 1.0365x over previous
//
#include <hip/hip_runtime.h>
#include <cfloat>
#include <cstdint>

// ---------------- problem constants ----------------
#define B_BATCH 32
#define D_DIM   256
#define HW      1024
#define N_POS   32768
#define K_CODES 1024
#define DECAY_F   0.99f
#define ONE_M_DECAY 0.01f
#define EPS_F   1e-5f

// ---------------- output layout (floats) ----------------
#define OUT_Q    0                         // 8388608  quantized_st (B,C,H,W)
#define OUT_LOSS 8388608                   // 1
#define OUT_PERP 8388609                   // 1
#define OUT_CB   8388610                   // 262144   new_codebook
#define OUT_NCS  8650754                   // 1024     new_cluster_size
#define OUT_EDW  8651778                   // 262144   new_ema_dw (dw scratch first)

// OUT_Q region doubles as z bf16 hi/lo scratch (exactly 33,554,432 bytes):
// ztrans writes zhi (16 MB) + zlo (16 MB); argmin_gemm + dw read them;
// tail_fused overwrites the region with the real output at the end.

// ---------------- workspace layout (bytes) ----------------
#define WS_COUNTS  0          // 1024*4
#define WS_ZNORM   4096       // 4   (sum of ||z||^2, fp32)
#define WS_BSUM    4100       // 4   (sum of best distances)
#define WS_MEMSET  4104       // bytes zeroed at launch
#define WS_CBNORM  4352       // 1024*4
#define WS_OFFS    8448       // 1024*4 (int)
#define WS_CURSOR  12544      // 1024*4 (int)
#define WS_IDX     16640      // 32768*4 (int)
#define WS_SORTED  147712     // 32768*4 (int)
#define WS_CBHI    278784     // 262144*2
#define WS_CBLO    803072     // 262144*2
#define WS_PART    1327360    // 32768*4*8 = 1048576 (u64 partial keys; region 2MB)
#define WS_SCODE   3424512    // 32768*4 (int, code of each sorted slot)
#define WS_TOTAL   3555584

typedef short s16x8 __attribute__((ext_vector_type(8)));
typedef float f32x4 __attribute__((ext_vector_type(4)));
typedef unsigned long long u64;

__device__ __forceinline__ ushort f2bf_rne(float x) {
    uint u = __float_as_uint(x);
    uint r = (u + 0x7FFF + ((u >> 16) & 1)) >> 16;
    return (ushort)r;
}
__device__ __forceinline__ float bf2f(ushort h) {
    return __uint_as_float(((uint)h) << 16);
}

// async global->LDS, 16 B per lane; LDS dst = wave-uniform base + lane*16
__device__ __forceinline__ void gload16(const void* g, void* l) {
    __builtin_amdgcn_global_load_lds(
        (const __attribute__((address_space(1))) unsigned*)(uintptr_t)g,
        (__attribute__((address_space(3))) unsigned*)(uintptr_t)l, 16, 0, 0);
}

// ============================================================
// prep_ztrans: fused.
//  blocks [0,512):  z (d-major) -> zhi/zlo bf16 (position-major) + sum ||z||^2
//  blocks [512,768): codebook fp32 -> bf16 hi/lo + row norms
__global__ __launch_bounds__(256) void prep_ztrans(const float* __restrict__ z,
                                                   const float* __restrict__ cb,
                                                   ushort* __restrict__ zhi,
                                                   ushort* __restrict__ zlo,
                                                   ushort* __restrict__ cbhi,
                                                   ushort* __restrict__ cblo,
                                                   float* __restrict__ cbnorm,
                                                   float* __restrict__ znorm_acc) {
    __shared__ float Zs[32][65];
    __shared__ float red[256];
    const int tid = threadIdx.x;

    if (blockIdx.x >= 512) {   // ---- prep part ----
        int wave = tid >> 6;
        int lane = tid & 63;
        int k = (blockIdx.x - 512) * 4 + wave;
        float4 v = *(const float4*)&cb[(size_t)k * D_DIM + lane * 4];
        ushort4 h, l;
        h.x = f2bf_rne(v.x); l.x = f2bf_rne(v.x - bf2f(h.x));
        h.y = f2bf_rne(v.y); l.y = f2bf_rne(v.y - bf2f(h.y));
        h.z = f2bf_rne(v.z); l.z = f2bf_rne(v.z - bf2f(h.z));
        h.w = f2bf_rne(v.w); l.w = f2bf_rne(v.w - bf2f(h.w));
        *(ushort4*)&cbhi[(size_t)k * D_DIM + lane * 4] = h;
        *(ushort4*)&cblo[(size_t)k * D_DIM + lane * 4] = l;
        float s = v.x * v.x + v.y * v.y + v.z * v.z + v.w * v.w;
        #pragma unroll
        for (int off = 32; off >= 1; off >>= 1) s += __shfl_xor(s, off);
        if (lane == 0) cbnorm[k] = s;
        return;
    }

    // ---- ztrans part ----
    const int n0  = blockIdx.x * 64;
    const int b   = n0 >> 10;
    const int hw0 = n0 & 1023;
    const float* zb = z + (size_t)b * (D_DIM * HW) + hw0;

    const int zn = tid & 63;
    const int zdb = (tid >> 6) * 8;
    const int n  = tid >> 2;
    const int dq = tid & 3;
    float zsum = 0.f;

    for (int d0 = 0; d0 < D_DIM; d0 += 32) {
        __syncthreads();
        #pragma unroll
        for (int j = 0; j < 8; ++j)
            Zs[zdb + j][zn] = zb[(size_t)(d0 + zdb + j) * HW + zn];
        __syncthreads();
        s16x8 hv, lv;
        #pragma unroll
        for (int j = 0; j < 8; ++j) {
            float f = Zs[dq * 8 + j][n];
            zsum += f * f;
            ushort hb = f2bf_rne(f);
            ushort lb = f2bf_rne(f - bf2f(hb));
            hv[j] = (short)hb;
            lv[j] = (short)lb;
        }
        *(s16x8*)&zhi[(size_t)(n0 + n) * D_DIM + d0 + dq * 8] = hv;
        *(s16x8*)&zlo[(size_t)(n0 + n) * D_DIM + d0 + dq * 8] = lv;
    }
    red[tid] = zsum;
    __syncthreads();
    for (int s2 = 128; s2 >= 1; s2 >>= 1) {
        if (tid < s2) red[tid] += red[tid + s2];
        __syncthreads();
    }
    if (tid == 0) atomicAdd(znorm_acc, red[0]);
}

// ============================================================
// argmin_gemm v5: 256 codes x 256 positions per block, 8 waves (2 code-halves
// x 4 pos-quarters), each wave M8N4 (128 codes x 64 pos), 3-term bf16 MFMA,
// K-step 32. Intensity: 96 MFMA / 24 ds_read_b128 per wave-step (4.0 MFMA per
// read, vs 3.0 for M4N4) -> total ds_reads drop 25%, staging bytes 50%.
// Ring-2 of 64 KB buffers = 128 KB LDS, 1 block/CU (2 waves/SIMD).
//
// Per-step ledger (single barrier):
//   vmcnt(0)   : own stage(t) writes landed (stage(t+1) not yet issued)
//   s_barrier  : publishes stage(t); also proves all step t-1 reads done
//   stage(t+1) -> other buffer, interleaved 2 gloads per phase
//   4 phases: P0 reads B[0..3] + A-pair 0 -> 24 MFMA; P1..P3 read one
//   A-pair each -> 24 MFMA (dep-shaped, setprio-wrapped)
//
// XCD swizzle: blk&7 = XCD; within an XCD, 4 consecutive blocks share the
// same pos-tile (B stays hot in that XCD's L2 across all 4 code tiles).
__global__ __launch_bounds__(512, 2) void argmin_gemm(const ushort* __restrict__ cbhi,
                                                      const ushort* __restrict__ cblo,
                                                      const ushort* __restrict__ zhi,
                                                      const ushort* __restrict__ zlo,
                                                      const float* __restrict__ cbnorm,
                                                      u64* __restrict__ partial) {
    // 2 x 65536 B ring (kred for the final reduction aliases buffer 0)
    __shared__ __align__(16) ushort lds[65536];   // 131072 bytes

    const int tid  = threadIdx.x;
    const int wave = tid >> 6;
    const int lane = tid & 63;
    const int col  = lane & 15;
    const int lg   = lane >> 4;
    const int wr   = wave >> 2;          // code half 0..1 (128 codes)
    const int wc   = wave & 3;           // position quarter 0..3 (64 positions)
    const int blk  = blockIdx.x;
    const int mt = (blk >> 3) & 3;                       // code tile (256 codes)
    const int pt = (blk & 7) | ((blk >> 5) << 3);        // position tile (256 pos)

    // ---- staging: buffer layout (64 KB): Ahi[0,16K) Alo[16K,32K)
    // Bhi[32K,48K) Blo[48K,64K). Each region = 256 rows x 64 B; two calls of
    // 128 rows each. Thread: srow = tid>>2 (0..127), slot G = tid&3; LDS slot
    // (row,G) holds logical 16B-group G ^ ((row>>1)&3) (read uses same XOR).
    const int srow = tid >> 2;
    const int G    = tid & 3;
    const int sg   = (G ^ ((srow >> 1) & 3)) * 16;   // swizzled source byte group
    const char* pAh = (const char*)cbhi + (size_t)(mt * 256 + srow) * 512 + sg;
    const char* pAl = (const char*)cblo + (size_t)(mt * 256 + srow) * 512 + sg;
    const char* pBh = (const char*)zhi  + (size_t)(pt * 256 + srow) * 512 + sg;
    const char* pBl = (const char*)zlo  + (size_t)(pt * 256 + srow) * 512 + sg;
    char* const ldsw = (char*)lds + wave * 1024;      // wave-uniform dest base

    // one quarter of a step's staging (2 gloads); q selects the region
    auto stage_q = [&](int kt, int bsel, int q) {
        char* d = ldsw + bsel * 65536;
        const int kb = kt * 64;
        if (q == 0)      { gload16(pAh + kb, d);         gload16(pAh + kb + 65536, d + 8192);  }
        else if (q == 1) { gload16(pAl + kb, d + 16384); gload16(pAl + kb + 65536, d + 24576); }
        else if (q == 2) { gload16(pBh + kb, d + 32768); gload16(pBh + kb + 65536, d + 40960); }
        else             { gload16(pBl + kb, d + 49152); gload16(pBl + kb + 65536, d + 57344); }
    };

    // ---- fragment read offsets (bytes); swizzle matches stage.
    const char* ldsc = (const char*)lds;
    const int swz  = (lg ^ ((col >> 1) & 3)) * 16;
    const int aoff = (wr * 128 + col) * 64 + swz;    // in Ahi region (row < 256)
    const int boff = (wc * 64 + col) * 64 + swz;     // in Bhi region (row < 256)

    f32x4 acc[8][4];
    #pragma unroll
    for (int mi = 0; mi < 8; ++mi)
        #pragma unroll
        for (int ni = 0; ni < 4; ++ni) acc[mi][ni] = {0.f, 0.f, 0.f, 0.f};

    // prologue: tile 0 in flight (8 gloads)
    stage_q(0, 0, 0); stage_q(0, 0, 1); stage_q(0, 0, 2); stage_q(0, 0, 3);

// 3-term MFMA for one (mi,ni) with explicit A regs; literal mi/ni only.
#define MM3A(AH, AL, mi, ni)                                                                   \
    acc[mi][ni] = __builtin_amdgcn_mfma_f32_16x16x32_bf16(AH, bh[ni], acc[mi][ni], 0, 0, 0);   \
    acc[mi][ni] = __builtin_amdgcn_mfma_f32_16x16x32_bf16(AH, bl[ni], acc[mi][ni], 0, 0, 0);   \
    acc[mi][ni] = __builtin_amdgcn_mfma_f32_16x16x32_bf16(AL, bh[ni], acc[mi][ni], 0, 0, 0);
#define ROW3(AH, AL, mi) MM3A(AH, AL, mi, 0) MM3A(AH, AL, mi, 1) MM3A(AH, AL, mi, 2) MM3A(AH, AL, mi, 3)

    #pragma unroll
    for (int t = 0; t < 8; ++t) {
        asm volatile("s_waitcnt vmcnt(0)" ::: "memory");
        __builtin_amdgcn_s_barrier();
        __builtin_amdgcn_sched_barrier(0);

        const char* bp = ldsc + (t & 1) * 65536;
        const int nb = (t + 1) & 1;
        s16x8 bh[4], bl[4];
        s16x8 ah0, al0, ah1, al1;

        // ---- P0: all B operands + A-pair 0 (m0,m1); stage quarter 0
        bh[0] = *(const s16x8*)(bp + 32768 + boff);
        bl[0] = *(const s16x8*)(bp + 49152 + boff);
        bh[1] = *(const s16x8*)(bp + 32768 + boff + 1024);
        bl[1] = *(const s16x8*)(bp + 49152 + boff + 1024);
        bh[2] = *(const s16x8*)(bp + 32768 + boff + 2048);
        bl[2] = *(const s16x8*)(bp + 49152 + boff + 2048);
        bh[3] = *(const s16x8*)(bp + 32768 + boff + 3072);
        bl[3] = *(const s16x8*)(bp + 49152 + boff + 3072);
        ah0 = *(const s16x8*)(bp + aoff);
        al0 = *(const s16x8*)(bp + 16384 + aoff);
        ah1 = *(const s16x8*)(bp + aoff + 1024);
        al1 = *(const s16x8*)(bp + 16384 + aoff + 1024);
        if (t < 7) stage_q(t + 1, nb, 0);
        __builtin_amdgcn_s_setprio(1);
        ROW3(ah0, al0, 0) ROW3(ah1, al1, 1)
        __builtin_amdgcn_s_setprio(0);

        // ---- P1: A-pair 1 (m2,m3); stage quarter 1
        ah0 = *(const s16x8*)(bp + aoff + 2048);
        al0 = *(const s16x8*)(bp + 16384 + aoff + 2048);
        ah1 = *(const s16x8*)(bp + aoff + 3072);
        al1 = *(const s16x8*)(bp + 16384 + aoff + 3072);
        if (t < 7) stage_q(t + 1, nb, 1);
        __builtin_amdgcn_s_setprio(1);
        ROW3(ah0, al0, 2) ROW3(ah1, al1, 3)
        __builtin_amdgcn_s_setprio(0);

        // ---- P2: A-pair 2 (m4,m5); stage quarter 2
        ah0 = *(const s16x8*)(bp + aoff + 4096);
        al0 = *(const s16x8*)(bp + 16384 + aoff + 4096);
        ah1 = *(const s16x8*)(bp + aoff + 5120);
        al1 = *(const s16x8*)(bp + 16384 + aoff + 5120);
        if (t < 7) stage_q(t + 1, nb, 2);
        __builtin_amdgcn_s_setprio(1);
        ROW3(ah0, al0, 4) ROW3(ah1, al1, 5)
        __builtin_amdgcn_s_setprio(0);

        // ---- P3: A-pair 3 (m6,m7); stage quarter 3
        ah0 = *(const s16x8*)(bp + aoff + 6144);
        al0 = *(const s16x8*)(bp + 16384 + aoff + 6144);
        ah1 = *(const s16x8*)(bp + aoff + 7168);
        al1 = *(const s16x8*)(bp + 16384 + aoff + 7168);
        if (t < 7) stage_q(t + 1, nb, 3);
        __builtin_amdgcn_s_setprio(1);
        ROW3(ah0, al0, 6) ROW3(ah1, al1, 7)
        __builtin_amdgcn_s_setprio(0);
    }
#undef ROW3
#undef MM3A

    // ---- argmin epilogue (C layout: code = kbase + mi*16 + lg*4 + r,
    // pos = pt*256 + wc*64 + ni*16 + col)
    const int kbase = mt * 256 + wr * 128;
    u64 best[4] = {~0ull, ~0ull, ~0ull, ~0ull};
    #pragma unroll
    for (int mi = 0; mi < 8; ++mi) {
        float4 cn = *(const float4*)&cbnorm[kbase + mi * 16 + lg * 4];
        const float* cnp = (const float*)&cn;
        #pragma unroll
        for (int ni = 0; ni < 4; ++ni) {
            #pragma unroll
            for (int r = 0; r < 4; ++r) {
                float dist = cnp[r] - 2.f * acc[mi][ni][r];
                uint ub = __float_as_uint(dist);
                ub = ub ^ (uint)(((int)ub >> 31) | 0x80000000);
                u64 key = ((u64)ub << 32) | (uint)(kbase + mi * 16 + lg * 4 + r);
                if (key < best[ni]) best[ni] = key;
            }
        }
    }
    #pragma unroll
    for (int ni = 0; ni < 4; ++ni) {
        u64 o = __shfl_xor(best[ni], 16); if (o < best[ni]) best[ni] = o;
        o = __shfl_xor(best[ni], 32); if (o < best[ni]) best[ni] = o;
    }
    // cross-wave min over the 2 code halves; kred aliases buffer 0 (bytes
    // 0..4095; final step read buffer 1, and buffer 0's last reads were step
    // 6 -- every wave passed step 7's barrier since).
    u64* kredp = (u64*)lds;
    if (lane < 16) {
        #pragma unroll
        for (int ni = 0; ni < 4; ++ni)
            kredp[(wc * 64 + ni * 16 + lane) * 2 + wr] = best[ni];
    }
    __syncthreads();
    if (tid < 256) {
        u64 a = kredp[tid * 2 + 0];
        u64 b = kredp[tid * 2 + 1]; if (b < a) a = b;
        partial[(size_t)(pt * 256 + tid) * 4 + mt] = a;
    }
}

// ============================================================
// combine: min over 4 code-tile partials -> idx; LDS histogram -> counts;
// decode best distance -> block sum -> Sum(bestd) for the loss.
__global__ __launch_bounds__(256) void combine_kernel(const u64* __restrict__ partial,
                                                      int* __restrict__ idx,
                                                      float* __restrict__ counts,
                                                      float* __restrict__ bsum_acc) {
    __shared__ int hist[1024];
    __shared__ float red[256];
    const int tid = threadIdx.x;
    for (int j = tid; j < 1024; j += 256) hist[j] = 0;
    __syncthreads();
    int n = blockIdx.x * 256 + tid;
    const u64* p = partial + (size_t)n * 4;
    u64 m = p[0];
    #pragma unroll
    for (int j = 1; j < 4; ++j) { u64 v = p[j]; if (v < m) m = v; }
    int k = (int)(m & 1023u);
    idx[n] = k;
    atomicAdd(&hist[k], 1);
    // decode monotone u32 -> f32 distance
    uint ub = (uint)(m >> 32);
    uint u = (ub & 0x80000000u) ? (ub ^ 0x80000000u) : ~ub;
    red[tid] = __uint_as_float(u);
    __syncthreads();
    for (int s2 = 128; s2 >= 1; s2 >>= 1) {
        if (tid < s2) red[tid] += red[tid + s2];
        __syncthreads();
    }
    if (tid == 0) atomicAdd(bsum_acc, red[0]);
    for (int j = tid; j < 1024; j += 256) {
        int c = hist[j];
        if (c) atomicAdd(&counts[j], (float)c);
    }
}

// ============================================================
// small: new_cluster_size, perplexity, ntot, loss, prefix-scan offsets/cursor.
__global__ __launch_bounds__(1024) void small_kernel(const float* __restrict__ ema_cs,
                                                     const float* __restrict__ counts,
                                                     const float* __restrict__ znorm,
                                                     const float* __restrict__ bsum,
                                                     float* __restrict__ out_ncs,
                                                     float* __restrict__ out_perp,
                                                     float* __restrict__ out_loss,
                                                     float* __restrict__ ntot_ws,
                                                     int* __restrict__ offsets,
                                                     int* __restrict__ cursor) {
    __shared__ float s1[1024];
    __shared__ float s2[1024];
    __shared__ int   s3[1024];
    int k = threadIdx.x;
    float cnt = counts[k];
    float ncs = ema_cs[k] * DECAY_F + ONE_M_DECAY * cnt;
    out_ncs[k] = ncs;
    float p = cnt / (float)N_POS;
    s1[k] = ncs;
    s2[k] = p * logf(p + 1e-10f);
    int c = (int)cnt;
    s3[k] = c;
    __syncthreads();
    for (int off = 1; off < 1024; off <<= 1) {
        int v = (k >= off) ? s3[k - off] : 0;
        __syncthreads();
        s3[k] += v;
        __syncthreads();
    }
    int excl = s3[k] - c;
    offsets[k] = excl;
    cursor[k] = excl;
    for (int st = 512; st >= 1; st >>= 1) {
        if (k < st) { s1[k] += s1[k + st]; s2[k] += s2[k + st]; }
        __syncthreads();
    }
    if (k == 0) {
        ntot_ws[0] = s1[0];
        out_perp[0] = expf(-s2[0]);
        out_loss[0] = 0.25f * (znorm[0] + bsum[0]) / 8388608.0f;
    }
}

// ============================================================
// scatter: block-aggregated bucket sort; also zeroes the dw scratch region.
__global__ __launch_bounds__(256) void scatter_kernel(const int* __restrict__ idx,
                                                      int* __restrict__ cursor,
                                                      int* __restrict__ sorted,
                                                      int* __restrict__ scode,
                                                      float* __restrict__ dw_zero) {
    __shared__ int hist[1024];
    __shared__ int base_s[1024];
    const int tid = threadIdx.x;
    // zero the dw scratch (262144 floats / 128 blocks = 8 per thread)
    {
        float4 z4 = {0.f, 0.f, 0.f, 0.f};
        size_t e = ((size_t)blockIdx.x * 256 + tid) * 8;
        *(float4*)&dw_zero[e] = z4;
        *(float4*)&dw_zero[e + 4] = z4;
    }
    for (int j = tid; j < 1024; j += 256) hist[j] = 0;
    __syncthreads();
    int n = blockIdx.x * 256 + tid;
    int k = idx[n];
    atomicAdd(&hist[k], 1);
    __syncthreads();
    for (int j = tid; j < 1024; j += 256) {
        int c = hist[j];
        if (c) base_s[j] = atomicAdd(&cursor[j], c);
        hist[j] = 0;
    }
    __syncthreads();
    int rank = atomicAdd(&hist[k], 1);
    int pos = base_s[k] + rank;
    sorted[pos] = n;
    scode[pos] = k;
}

// ============================================================
// dw_chunk: uniform chunks of the SORTED array. Complete segments store
// directly; chunk-spanning runs atomicAdd. dw pre-zeroed by scatter.
#define DW_CHUNK 64
__global__ __launch_bounds__(256) void dw_chunk_kernel(const ushort* __restrict__ zhi,
                                                       const ushort* __restrict__ zlo,
                                                       const int* __restrict__ sorted,
                                                       const int* __restrict__ scode,
                                                       const int* __restrict__ offsets,
                                                       const float* __restrict__ counts,
                                                       float* __restrict__ dw) {
    __shared__ int sid[DW_CHUNK];
    __shared__ int sk[DW_CHUNK];
    const int tid = threadIdx.x;
    const int p0 = blockIdx.x * DW_CHUNK;
    if (tid < DW_CHUNK) {
        sid[tid] = sorted[p0 + tid];
        sk[tid]  = scode[p0 + tid];
    }
    __syncthreads();
    float acc = 0.f;
    int runstart = 0;
    #pragma unroll 4
    for (int i = 0; i < DW_CHUNK; ++i) {
        int id = sid[i];
        float zv = bf2f(zhi[(size_t)id * D_DIM + tid]) + bf2f(zlo[(size_t)id * D_DIM + tid]);
        acc += zv;
        bool end = (i == DW_CHUNK - 1) || (sk[i + 1] != sk[i]);
        if (end) {
            int k = sk[i];
            int off = offsets[k];
            int cnt = (int)counts[k];
            if (p0 + runstart == off && p0 + i == off + cnt - 1)
                dw[(size_t)k * D_DIM + tid] = acc;
            else
                atomicAdd(&dw[(size_t)k * D_DIM + tid], acc);
            acc = 0.f;
            runstart = i + 1;
        }
    }
}

// ============================================================
// tail_fused: blocks [0,512) = fuse_lite (gather codebook rows -> outq,
// d-major; zp + (q - zp) == q to 1 ulp so no z read); blocks [512,1536) =
// finalize_rows (new_ema_dw in place and new_codebook). Both depend only on
// dw_chunk having completed; merged to save one dispatch.
__global__ __launch_bounds__(256) void tail_fused(const float* __restrict__ cb,
                                                  const int* __restrict__ idx,
                                                  float* __restrict__ outq,
                                                  const float* __restrict__ ema_dw,
                                                  const float* __restrict__ out_ncs,
                                                  const float* __restrict__ ntot_ws,
                                                  float* __restrict__ out_edw,
                                                  float* __restrict__ out_cb) {
    const int tid = threadIdx.x;
    if (blockIdx.x >= 512) {      // ---- finalize part ----
        int k = blockIdx.x - 512;
        int d = tid;
        float ncs = out_ncs[k];
        float nt = ntot_ws[0];
        float csz = (ncs + EPS_F) / (nt + (float)K_CODES * EPS_F) * nt;
        size_t e = (size_t)k * D_DIM + d;
        float ed = ema_dw[e] * DECAY_F + ONE_M_DECAY * out_edw[e];
        out_edw[e] = ed;
        out_cb[e] = ed / csz;
        return;
    }

    // ---- fuse part ----
    __shared__ float Qs[32][65];
    __shared__ int kidx[64];
    const int n0  = blockIdx.x * 64;
    const int b   = n0 >> 10;
    const int hw0 = n0 & 1023;
    float* ob = outq + (size_t)b * (D_DIM * HW) + hw0;

    if (tid < 64) kidx[tid] = idx[n0 + tid];

    for (int d0 = 0; d0 < D_DIM; d0 += 32) {
        __syncthreads();   // protects Qs reuse (and kidx on first iter)
        #pragma unroll
        for (int h = 0; h < 2; ++h) {
            int s  = tid + 256 * h;
            int n  = s >> 3;
            int dq = s & 7;
            int k  = kidx[n];
            float4 q = *(const float4*)&cb[(size_t)k * D_DIM + d0 + dq * 4];
            Qs[dq * 4 + 0][n] = q.x;
            Qs[dq * 4 + 1][n] = q.y;
            Qs[dq * 4 + 2][n] = q.z;
            Qs[dq * 4 + 3][n] = q.w;
        }
        __syncthreads();
        #pragma unroll
        for (int j = 0; j < 8; ++j) {
            int v = tid + 256 * j;
            int d = v >> 6;
            int n = v & 63;
            ob[(size_t)(d0 + d) * HW + n] = Qs[d][n];
        }
    }
}

// ============================================================
extern "C" void kernel_launch(void* const* d_in, const int* in_sizes, int n_in,
                              void* d_out, int out_size, void* d_ws, size_t ws_size,
                              hipStream_t stream) {
    const float* z       = (const float*)d_in[0];
    const float* cb      = (const float*)d_in[1];
    const float* ema_cs  = (const float*)d_in[2];
    const float* ema_dw  = (const float*)d_in[3];
    float* out = (float*)d_out;

    char* ws = (char*)d_ws;
    float* ws_counts = (float*)(ws + WS_COUNTS);
    float* ws_znorm  = (float*)(ws + WS_ZNORM);
    float* ws_bsum   = (float*)(ws + WS_BSUM);
    float* ws_cbnorm = (float*)(ws + WS_CBNORM);
    int*   ws_offs   = (int*)(ws + WS_OFFS);
    int*   ws_cursor = (int*)(ws + WS_CURSOR);
    int*   ws_idx    = (int*)(ws + WS_IDX);
    int*   ws_sorted = (int*)(ws + WS_SORTED);
    ushort* ws_cbhi  = (ushort*)(ws + WS_CBHI);
    ushort* ws_cblo  = (ushort*)(ws + WS_CBLO);
    u64*   ws_part   = (u64*)(ws + WS_PART);
    int*   ws_scode  = (int*)(ws + WS_SCODE);

    // zhi/zlo scratch lives in the OUT_Q region (exactly 32 MB)
    ushort* zhi = (ushort*)out;
    ushort* zlo = zhi + 8388608;

    hipMemsetAsync(d_ws, 0, WS_MEMSET, stream);

    prep_ztrans<<<768, 256, 0, stream>>>(z, cb, zhi, zlo, ws_cbhi, ws_cblo,
                                         ws_cbnorm, ws_znorm);
    argmin_gemm<<<512, 512, 0, stream>>>(ws_cbhi, ws_cblo, zhi, zlo, ws_cbnorm, ws_part);
    combine_kernel<<<N_POS / 256, 256, 0, stream>>>(ws_part, ws_idx, ws_counts, ws_bsum);
    small_kernel<<<1, 1024, 0, stream>>>(ema_cs, ws_counts, ws_znorm, ws_bsum,
                                         out + OUT_NCS, out + OUT_PERP, out + OUT_LOSS,
                                         (float*)(ws + WS_ZNORM) + 1024, ws_offs, ws_cursor);
    scatter_kernel<<<N_POS / 256, 256, 0, stream>>>(ws_idx, ws_cursor, ws_sorted,
                                                    ws_scode, out + OUT_EDW);
    dw_chunk_kernel<<<N_POS / DW_CHUNK, 256, 0, stream>>>(zhi, zlo, ws_sorted, ws_scode,
                                                          ws_offs, ws_counts, out + OUT_EDW);
    tail_fused<<<1536, 256, 0, stream>>>(cb, ws_idx, out + OUT_Q, ema_dw, out + OUT_NCS,
                                         (float*)(ws + WS_ZNORM) + 1024,
                                         out + OUT_EDW, out + OUT_CB);
}